// Round 4
// baseline (1571.112 us; speedup 1.0000x reference)
//
#include <hip/hip_runtime.h>
#include <math.h>

// ============================================================================
// CapsuleNet forward, round 17.
// R16 post-mortem: fused routing at 973us, FETCH 1.98GB = zero rwh reuse.
//   Cause: c-major block order (c=bid>>9) made the resident window span all
//   512 b for one c -> per-XCD WS = full u16 (9.4MB > 4MB L2) + 64 staggered
//   rwh streams -> L2 thrash, every block refetched 295KB from HBM.
// Fix: b-major order (c=bid%10, b=bid/10). Window = ~51 b x all 10 c ->
//   per-XCD WS = all rwh (2.95MB, L2-resident, constantly re-hit) + ~1.2MB
//   sliding u16 window. rwh fetched ~once per XCD (~24MB chip), u16 once.
//   Loads become L2 hits; 8 waves/CU hide ~200cyc latency.
// prim: R15 kept (3-buf depth-2 counted-vmcnt; 128x128-structure ceiling).
// conv1 GEMM / im2col / wtrans / squash / rwprep / classes / fc unchanged.
// ============================================================================

typedef _Float16 f16;
typedef _Float16 f16x8 __attribute__((ext_vector_type(8)));
typedef _Float16 f16x4 __attribute__((ext_vector_type(4)));
typedef float f32x4 __attribute__((ext_vector_type(4)));

__device__ __forceinline__ void gl_lds16(const void* g, void* l) {
  __builtin_amdgcn_global_load_lds(
      (const __attribute__((address_space(1))) void*)g,
      (__attribute__((address_space(3))) void*)l, 16, 0, 0);
}

// --------- im2col: x[512,1,28,28] fp32 -> A16[m=204800][96] f16 ------------
__global__ void im2col_kernel(const float* __restrict__ x, f16* __restrict__ A)
{
  const int c = blockIdx.x * 256 + threadIdx.x;    // 2,457,600 exact
  const int m = c / 12, kc = c - m * 12;
  const int b = m / 400, rem = m - b * 400;
  const int oy = rem / 20, ox = rem - oy * 20;
  const float* xb = x + b * 784;
  f16x8 v;
#pragma unroll
  for (int j = 0; j < 8; ++j) {
    const int k = kc * 8 + j;
    float val = 0.f;
    if (k < 81) {
      const int ky = k / 9, kx = k - ky * 9;
      val = xb[(oy + ky) * 28 + ox + kx];
    }
    v[j] = (f16)val;
  }
  *(f16x8*)&A[(size_t)m * 96 + kc * 8] = v;
}

// --------- c1trans: conv1_w fp32 [256][81] -> wt1 f16 [256][96] (pad 0) ----
__global__ void c1trans_kernel(const float* __restrict__ w, f16* __restrict__ wt1)
{
  const int idx = blockIdx.x * 256 + threadIdx.x;  // 24576 exact
  const int oc = idx / 96, k = idx - oc * 96;
  wt1[idx] = (k < 81) ? (f16)w[oc * 81 + k] : (f16)0.f;
}

// --------- conv1 GEMM: ht[m][oc] = relu(A16 @ wt1^T + bias) ----------------
__global__ __launch_bounds__(256) void conv1_mfma_kernel(
    const f16* __restrict__ A, const f16* __restrict__ wt1,
    const float* __restrict__ bias, f16* __restrict__ ht)
{
  __shared__ f16 sm[8192];            // As[0..4096) | Bs[4096..8192)
  const int t = threadIdx.x;
  const int wv = t >> 6, lane = t & 63;
  const int id = blockIdx.x;
  const int mb = id >> 1, nb = id & 1;
  const int m0 = mb * 128, n0 = nb * 128;

  const int chunk = (lane & 3) ^ ((lane >> 3) & 3);
  long aoff[2], boff[2];
#pragma unroll
  for (int i = 0; i < 2; ++i) {
    const int r = wv * 32 + i * 16 + (lane >> 2);
    aoff[i] = (long)(m0 + r) * 192 + chunk * 16;
    boff[i] = (long)(n0 + r) * 192 + chunk * 16;
  }
  const char* ac = (const char*)A;
  const char* bc = (const char*)wt1;

  const int lrow = lane & 15, quad = lane >> 4;
  const int qx = quad ^ ((lrow >> 1) & 3);
  const int wm = wv & 1, wn = wv >> 1;
  f32x4 acc[4][4] = {};

  for (int s = 0; s < 3; ++s) {
    const long kstep = (long)s * 64;
    __syncthreads();
    {
      char* dA = (char*)sm + wv * 2048;
      char* dB = (char*)sm + 8192 + wv * 2048;
      gl_lds16(ac + aoff[0] + kstep, dA);
      gl_lds16(ac + aoff[1] + kstep, dA + 1024);
      gl_lds16(bc + boff[0] + kstep, dB);
      gl_lds16(bc + boff[1] + kstep, dB + 1024);
    }
    __syncthreads();
    const f16* As = sm;
    const f16* Bs = sm + 4096;
    f16x8 af[4], bf[4];
#pragma unroll
    for (int mt = 0; mt < 4; ++mt)
      af[mt] = *(const f16x8*)&As[(wm * 64 + mt * 16 + lrow) * 32 + qx * 8];
#pragma unroll
    for (int nt = 0; nt < 4; ++nt)
      bf[nt] = *(const f16x8*)&Bs[(wn * 64 + nt * 16 + lrow) * 32 + qx * 8];
#pragma unroll
    for (int mt = 0; mt < 4; ++mt)
#pragma unroll
      for (int nt = 0; nt < 4; ++nt)
        acc[mt][nt] = __builtin_amdgcn_mfma_f32_16x16x32_f16(
            af[mt], bf[nt], acc[mt][nt], 0, 0, 0);
  }

  // epilogue: ht[m*256 + oc] = relu(acc + bias[oc]) as f16 (NHWC, y/x in m)
#pragma unroll
  for (int nt = 0; nt < 4; ++nt) {
    const int n = n0 + wn * 64 + nt * 16 + lrow;          // col=lane&15
    const float bv = bias[n];
#pragma unroll
    for (int mt = 0; mt < 4; ++mt) {
      const int mbase = m0 + wm * 64 + mt * 16 + quad * 4; // row=quad*4+reg
#pragma unroll
      for (int rg = 0; rg < 4; ++rg)
        ht[(size_t)(mbase + rg) * 256 + n] =
            (f16)fmaxf(acc[mt][nt][rg] + bv, 0.f);
    }
  }
}

// --------- wtrans: prim_w fp32 [oc][ic][kykx] -> wt fp16 [oc][kykx][ic] ----
__global__ __launch_bounds__(256) void wtrans_kernel(
    const float* __restrict__ w, f16* __restrict__ wt)
{
  __shared__ float tile[64 * 83];
  const int oc = blockIdx.x;
  const int icq = blockIdx.y;
  const int t = threadIdx.x;
  const float* src = w + (size_t)oc * 20736 + (size_t)icq * 64 * 81;
  for (int idx = t; idx < 5184; idx += 256) {
    const int ici = idx / 81, kk = idx - ici * 81;
    tile[ici * 83 + kk] = src[idx];
  }
  __syncthreads();
  f16* dst = wt + (size_t)oc * 20736 + icq * 64;
  for (int idx = t; idx < 5184; idx += 256) {
    const int kk = idx >> 6, ici = idx & 63;
    dst[kk * 256 + ici] = (f16)tile[ici * 83 + kk];
  }
}

// ---------------- primary caps conv: MFMA implicit GEMM, split-K 8 ---------
// grid 2304 = 144 mb x 2 nb x 8 ks = exactly 3 rounds at 3 blocks/CU.
__global__ __launch_bounds__(256) void prim_mfma_kernel(
    const f16* __restrict__ ht, const f16* __restrict__ wt,
    f16* __restrict__ part)
{
  __shared__ f16 sm[24576];           // 48 KB: 3 buffers of [A 8KB | B 8KB]
  const int t = threadIdx.x;
  const int wv = t >> 6, lane = t & 63;
  const int id = blockIdx.x;
  const int ks = (id >> 3) & 7;                   // 8 K-slices
  const int nb = (id >> 6) & 1;
  const int mb = (id & 7) + 8 * (id >> 7);        // same-mb ids === mod 8
  const int m0 = mb * 128, n0 = nb * 128;

  const int chunk = (lane & 3) ^ ((lane >> 3) & 3);
  long aoff[2], boff[2];
#pragma unroll
  for (int i = 0; i < 2; ++i) {
    const int r = wv * 32 + i * 16 + (lane >> 2);
    const int m = m0 + r;
    const int b = m / 36, pos = m - b * 36;
    const int oy = pos / 6, ox = pos - oy * 6;
    aoff[i] = (long)(((b * 20 + 2 * oy) * 20 + 2 * ox) * 256) * 2 + chunk * 16;
    boff[i] = (long)(n0 + r) * 41472 + chunk * 16;   // oc*81*256*2
  }
  const char* htc = (const char*)ht;
  const char* wtc = (const char*)wt;

  const int lrow = lane & 15, quad = lane >> 4;
  const int qx = quad ^ ((lrow >> 1) & 3);
  const int wm = wv & 1, wn = wv >> 1;
  f32x4 acc[4][4] = {};

  const int s0 = ks * 81;             // 81 stages per slice

#define STAGE(S, BUFB)                                                        \
  {                                                                           \
    const int kykx = (S) >> 3, icb = (S) & 7;                                 \
    const int ky = kykx / 9, kx = kykx - ky * 9;                              \
    const long astep = (long)((((ky * 20 + kx) * 256) + icb * 32) * 2);       \
    const long bstep = (long)(((kykx * 256) + icb * 32) * 2);                 \
    char* dA = (char*)sm + (BUFB) + wv * 2048;                                \
    char* dB = (char*)sm + (BUFB) + 8192 + wv * 2048;                        \
    gl_lds16(htc + aoff[0] + astep, dA);                                      \
    gl_lds16(htc + aoff[1] + astep, dA + 1024);                               \
    gl_lds16(wtc + boff[0] + bstep, dB);                                      \
    gl_lds16(wtc + boff[1] + bstep, dB + 1024);                               \
  }

#define CONSUME(BUFI)                                                         \
  {                                                                           \
    const f16* As = sm + (BUFI);                                              \
    const f16* Bs = sm + (BUFI) + 4096;                                       \
    f16x8 af[4], bf[4];                                                       \
    _Pragma("unroll") for (int mt = 0; mt < 4; ++mt)                          \
        af[mt] = *(const f16x8*)&As[(wm * 64 + mt * 16 + lrow) * 32 + qx * 8];\
    _Pragma("unroll") for (int nt = 0; nt < 4; ++nt)                          \
        bf[nt] = *(const f16x8*)&Bs[(wn * 64 + nt * 16 + lrow) * 32 + qx * 8];\
    _Pragma("unroll") for (int mt = 0; mt < 4; ++mt)                          \
        _Pragma("unroll") for (int nt = 0; nt < 4; ++nt)                      \
            acc[mt][nt] = __builtin_amdgcn_mfma_f32_16x16x32_f16(             \
                af[mt], bf[nt], acc[mt][nt], 0, 0, 0);                        \
  }

  // depth-2 pipeline, 3 buffers (byte offsets 0 / 16384 / 32768)
  STAGE(s0, 0);
  STAGE(s0 + 1, 16384);
  int bS = 32768;                     // stage target:   (K+2)%3
  int bC = 0;                         // consume buffer:  K   %3
  for (int K = 0; K < 79; ++K) {
    asm volatile("s_waitcnt vmcnt(4)" ::: "memory");  // own stage-K writes done
    __builtin_amdgcn_s_barrier();                     // publish to all waves
    asm volatile("" ::: "memory");
    STAGE(s0 + K + 2, bS);
    __builtin_amdgcn_s_setprio(1);
    CONSUME(bC >> 1);
    __builtin_amdgcn_s_setprio(0);
    bS += 16384; if (bS == 49152) bS = 0;
    bC += 16384; if (bC == 49152) bC = 0;
  }
  // K = 79: stages 79,80 in flight; wait 79 (4 newest = stage 80 may fly)
  asm volatile("s_waitcnt vmcnt(4)" ::: "memory");
  __builtin_amdgcn_s_barrier();
  asm volatile("" ::: "memory");
  __builtin_amdgcn_s_setprio(1);
  CONSUME(bC >> 1);
  __builtin_amdgcn_s_setprio(0);
  bC += 16384; if (bC == 49152) bC = 0;
  // K = 80: wait everything
  asm volatile("s_waitcnt vmcnt(0)" ::: "memory");
  __builtin_amdgcn_s_barrier();
  asm volatile("" ::: "memory");
  CONSUME(bC >> 1);
#undef STAGE
#undef CONSUME

  // epilogue: f16 partials, 8 slices of [18432][256], permuted np layout
  f16* pp = part + (size_t)ks * 4718592;
#pragma unroll
  for (int mt = 0; mt < 4; ++mt) {
    const int mbase = m0 + wm * 64 + mt * 16 + quad * 4;
#pragma unroll
    for (int nt = 0; nt < 4; ++nt) {
      const int n = n0 + wn * 64 + nt * 16 + lrow;
      const int np = (n & 31) * 8 + (n >> 5);
#pragma unroll
      for (int rg = 0; rg < 4; ++rg)
        pp[(size_t)(mbase + rg) * 256 + np] = (f16)acc[mt][nt][rg];
    }
  }
}

// --------- split-K(8) reduce + bias + squash -> u16[512][rs=pos*32+cc][8] --
__global__ void squash_kernel(const f16* __restrict__ part,
                              const float* __restrict__ bias,
                              f16* __restrict__ u16)
{
  const int tid = blockIdx.x * 256 + threadIdx.x;   // (b*36+pos)*32 + cc
  if (tid >= 512 * 36 * 32) return;
  const int cc = tid & 31;
  const int row = tid >> 5;                         // b*36 + pos
  const int b = row / 36;
  const int pos = row - b * 36;
  const f16* p = part + (size_t)row * 256 + cc * 8;
  float v[8] = {};
#pragma unroll
  for (int ksl = 0; ksl < 8; ++ksl) {
    const f16x8 a = *(const f16x8*)(p + (size_t)ksl * 4718592);
#pragma unroll
    for (int i = 0; i < 8; ++i) v[i] += (float)a[i];
  }
  float sq = 0.f;
#pragma unroll
  for (int i = 0; i < 8; ++i) {
    v[i] += bias[i * 32 + cc];
    sq = fmaf(v[i], v[i], sq);
  }
  const float scale = sq / ((1.f + sq) * sqrtf(sq));
  f16x8 st;
#pragma unroll
  for (int i = 0; i < 8; ++i) st[i] = (f16)(v[i] * scale);
  *(f16x8*)&u16[(size_t)(b * 1152 + pos * 32 + cc) * 8] = st;   // contiguous
}

// --------- rwprep: route_w f32 [c][r_true][8][16] -> rwh f16 [c][rs][8][16] -
// storage order rs = pos*32+cc  <->  r_true = cc*36+pos
__global__ void rwprep_kernel(const float* __restrict__ rw, f16* __restrict__ rwh)
{
  const int rs = blockIdx.x;            // [0,1152)
  const int c  = blockIdx.y;            // [0,10)
  const int t  = threadIdx.x;           // [0,128) = k*16+o
  const int pos = rs >> 5, cc = rs & 31;
  const int r_true = cc * 36 + pos;
  const float v = rw[(size_t)(c * 1152 + r_true) * 128 + t];
  rwh[(size_t)(c * 1152 + rs) * 128 + t] = (f16)v;
}

// ---------------- FUSED priors + dynamic routing, one block per (b,c) ------
// b-major bid: c = bid%10, b = bid/10 -> resident window covers all 10 c and
// ~51 b => per-XCD L2 WS = rwh (2.95MB, resident) + ~1.2MB u16 slide.
__device__ __forceinline__ float wave_sum(float v) {
#pragma unroll
  for (int off = 32; off > 0; off >>= 1) v += __shfl_xor(v, off);
  return v;
}
__device__ __forceinline__ float wave_max(float v) {
#pragma unroll
  for (int off = 32; off > 0; off >>= 1) v = fmaxf(v, __shfl_xor(v, off));
  return v;
}

__global__ __launch_bounds__(256, 2) void routing_kernel(
    const f16* __restrict__ u16, const f16* __restrict__ rwh,
    float* __restrict__ caps)
{
  const int c = blockIdx.x % 10;
  const int b = blockIdx.x / 10;
  const int t = threadIdx.x;
  const int wid = t >> 6;
  const int lane = t & 63;
  __shared__ float xred[4 * 17];

  float P[5][16];
  float lg[5];
  const int nk = (t < 128) ? 5 : 4;
#pragma unroll
  for (int k = 0; k < 5; ++k)
#pragma unroll
    for (int o = 0; o < 16; ++o) P[k][o] = 0.f;

  // ---- fused priors: P[k][o] = sum_kk u[b,rs,kk] * rwh[c,rs,kk,o] ----
  const f16* ub = u16 + (size_t)b * 9216;           // b*1152*8
  const f16* wb = rwh + (size_t)c * 147456;         // c*1152*128
#pragma unroll
  for (int k = 0; k < 5; ++k) {
    if (k < nk) {
      const int rs = t + (k << 8);
      const f16x8 uv = *(const f16x8*)&ub[(size_t)rs * 8];
      float uf[8];
#pragma unroll
      for (int i = 0; i < 8; ++i) uf[i] = (float)uv[i];
      const f16* wr = wb + (size_t)rs * 128;
#pragma unroll
      for (int kk = 0; kk < 8; ++kk) {
        const f16x8 w0 = *(const f16x8*)&wr[kk * 16];
        const f16x8 w1 = *(const f16x8*)&wr[kk * 16 + 8];
#pragma unroll
        for (int o = 0; o < 8; ++o) {
          P[k][o]     = fmaf(uf[kk], (float)w0[o], P[k][o]);
          P[k][o + 8] = fmaf(uf[kk], (float)w1[o], P[k][o + 8]);
        }
      }
    }
  }

  float v[16];
  {
    float sq = 0.f;
#pragma unroll
    for (int o = 0; o < 16; ++o) {
      float p = 0.f;
#pragma unroll
      for (int k = 0; k < 5; ++k) p += P[k][o];
      p = wave_sum(p);
      if (lane == 0) xred[wid * 17 + o] = p;
      v[o] = 0.f;
    }
    __syncthreads();
#pragma unroll
    for (int o = 0; o < 16; ++o) {
      const float s = (xred[o] + xred[17 + o] + xred[34 + o] + xred[51 + o]) *
                      (1.f / 1152.f);
      v[o] = s;
      sq = fmaf(s, s, sq);
    }
    const float scale = sq / ((1.f + sq) * sqrtf(sq));
#pragma unroll
    for (int o = 0; o < 16; ++o) v[o] *= scale;
    __syncthreads();
  }
#pragma unroll
  for (int k = 0; k < 5; ++k) {
    float a = 0.f;
#pragma unroll
    for (int o = 0; o < 16; ++o) a = fmaf(P[k][o], v[o], a);
    lg[k] = a;
  }

  for (int it = 1; it < 3; ++it) {
    float m = -1e30f;
#pragma unroll
    for (int k = 0; k < 5; ++k) if (k < nk) m = fmaxf(m, lg[k]);
    m = wave_max(m);
    if (lane == 0) xred[wid * 17 + 16] = m;
    __syncthreads();
    const float mx = fmaxf(fmaxf(xred[16], xred[17 + 16]),
                           fmaxf(xred[34 + 16], xred[51 + 16]));
    __syncthreads();
    float e[5];
#pragma unroll
    for (int k = 0; k < 5; ++k) e[k] = (k < nk) ? expf(lg[k] - mx) : 0.f;
    float pS = 0.f;
#pragma unroll
    for (int k = 0; k < 5; ++k) pS += e[k];
    pS = wave_sum(pS);
    if (lane == 0) xred[wid * 17 + 16] = pS;
#pragma unroll
    for (int o = 0; o < 16; ++o) {
      float p = 0.f;
#pragma unroll
      for (int k = 0; k < 5; ++k) p = fmaf(e[k], P[k][o], p);
      p = wave_sum(p);
      if (lane == 0) xred[wid * 17 + o] = p;
    }
    __syncthreads();
    const float S = xred[16] + xred[17 + 16] + xred[34 + 16] + xred[51 + 16];
    const float inv = 1.f / S;
    float sq = 0.f;
#pragma unroll
    for (int o = 0; o < 16; ++o) {
      const float s = (xred[o] + xred[17 + o] + xred[34 + o] + xred[51 + o]) * inv;
      v[o] = s;
      sq = fmaf(s, s, sq);
    }
    const float scale = sq / ((1.f + sq) * sqrtf(sq));
#pragma unroll
    for (int o = 0; o < 16; ++o) v[o] *= scale;
    __syncthreads();
    if (it < 2) {
#pragma unroll
      for (int k = 0; k < 5; ++k) {
        float a = 0.f;
#pragma unroll
        for (int o = 0; o < 16; ++o) a = fmaf(P[k][o], v[o], a);
        lg[k] += a;
      }
    }
  }
  if (t == 0) {
    float* cp = &caps[(b * 10 + c) * 16];
#pragma unroll
    for (int o = 0; o < 16; ++o) cp[o] = v[o];
  }
}

// --------- classes softmax + argmax one-hot mask ---------------------------
__global__ void classes_kernel(const float* __restrict__ caps,
                               float* __restrict__ out_classes,
                               float* __restrict__ d0)
{
  const int b = blockIdx.x * 256 + threadIdx.x;
  if (b >= 512) return;
  float nrm[10];
#pragma unroll
  for (int cc = 0; cc < 10; ++cc) {
    float sq = 0.f;
#pragma unroll
    for (int o = 0; o < 16; ++o) {
      const float vv = caps[(b * 10 + cc) * 16 + o];
      sq = fmaf(vv, vv, sq);
    }
    nrm[cc] = sqrtf(sq);
  }
  float mx = nrm[0]; int cs = 0;
#pragma unroll
  for (int cc = 1; cc < 10; ++cc)
    if (nrm[cc] > mx) { mx = nrm[cc]; cs = cc; }
  float e[10], ssum = 0.f;
#pragma unroll
  for (int cc = 0; cc < 10; ++cc) { e[cc] = expf(nrm[cc] - mx); ssum += e[cc]; }
  const float inv = 1.f / ssum;
#pragma unroll
  for (int cc = 0; cc < 10; ++cc) out_classes[b * 10 + cc] = e[cc] * inv;
#pragma unroll
  for (int cc = 0; cc < 10; ++cc)
#pragma unroll
    for (int o = 0; o < 16; ++o)
      d0[b * 160 + cc * 16 + o] = (cc == cs) ? caps[(b * 10 + cc) * 16 + o] : 0.f;
}

// --------- decoder GEMM: C[M,N] = act(A[M,K] @ W[N,K]^T + bias) ------------
__global__ __launch_bounds__(256, 2) void fc_kernel(
    const float* __restrict__ A, const float* __restrict__ W,
    const float* __restrict__ bias, float* __restrict__ C,
    int N, int K, int act)
{
  __shared__ float As[64][17];
  __shared__ float Ws[64][17];
  const int t = threadIdx.x;
  const int tm = t >> 4, tn = t & 15;
  const int m0 = blockIdx.y << 6, n0 = blockIdx.x << 6;
  const int lr = t >> 2, lq = (t & 3) << 2;
  float acc[4][4] = {};
  for (int k0 = 0; k0 < K; k0 += 16) {
    const float4 av = *(const float4*)&A[(m0 + lr) * K + k0 + lq];
    float4 wv = make_float4(0.f, 0.f, 0.f, 0.f);
    const int wn = n0 + lr;
    if (wn < N) wv = *(const float4*)&W[wn * K + k0 + lq];
    __syncthreads();
    As[lr][lq+0] = av.x; As[lr][lq+1] = av.y; As[lr][lq+2] = av.z; As[lr][lq+3] = av.w;
    Ws[lr][lq+0] = wv.x; Ws[lr][lq+1] = wv.y; Ws[lr][lq+2] = wv.z; Ws[lr][lq+3] = wv.w;
    __syncthreads();
#pragma unroll
    for (int kk = 0; kk < 16; ++kk) {
      float a[4], w[4];
#pragma unroll
      for (int i = 0; i < 4; ++i) a[i] = As[tm * 4 + i][kk];
#pragma unroll
      for (int j = 0; j < 4; ++j) w[j] = Ws[tn * 4 + j][kk];
#pragma unroll
      for (int i = 0; i < 4; ++i)
#pragma unroll
        for (int j = 0; j < 4; ++j) acc[i][j] = fmaf(a[i], w[j], acc[i][j]);
    }
  }
#pragma unroll
  for (int i = 0; i < 4; ++i) {
    const int m = m0 + tm * 4 + i;
#pragma unroll
    for (int j = 0; j < 4; ++j) {
      const int n = n0 + tn * 4 + j;
      if (n < N) {
        float vv = acc[i][j] + bias[n];
        vv = act ? (1.f / (1.f + expf(-vv))) : fmaxf(vv, 0.f);
        C[m * N + n] = vv;
      }
    }
  }
}

// ============================================================================
extern "C" void kernel_launch(void* const* d_in, const int* in_sizes, int n_in,
                              void* d_out, int out_size, void* d_ws, size_t ws_size,
                              hipStream_t stream)
{
  const float* x       = (const float*)d_in[0];
  const float* conv1_w = (const float*)d_in[1];
  const float* conv1_b = (const float*)d_in[2];
  const float* prim_w  = (const float*)d_in[3];
  const float* prim_b  = (const float*)d_in[4];
  const float* route_w = (const float*)d_in[5];
  const float* dec_w1  = (const float*)d_in[6];
  const float* dec_b1  = (const float*)d_in[7];
  const float* dec_w2  = (const float*)d_in[8];
  const float* dec_b2  = (const float*)d_in[9];
  const float* dec_w3  = (const float*)d_in[10];
  const float* dec_b3  = (const float*)d_in[11];
  float* out = (float*)d_out;

  char* ws = (char*)d_ws;
  f16*   ht   = (f16*)(ws);                        // 104,857,600 B
  f16*   wtp  = (f16*)(ws + 104857600);            //  10,616,832 B
  f16*   part = (f16*)(ws + 115474432);            //  75,497,472 B (8 f16 slices)
  f16*   A16  = (f16*)(ws + 115474432);            //  39,321,600 B (overlays
                                                   //  part; dead before prim)
  f16*   wt1  = (f16*)(ws + 190971904);            //      49,152 B
  f16*   u16  = (f16*)(ws + 191021056);            //   9,437,184 B
  f16*   rwh  = (f16*)(ws);                        //   2,949,120 B (overlays
                                                   //  ht, dead after prim)
  float* caps = (float*)(ws + 200458240);          // 327,680 B
  float* d0   = (float*)(ws + 200785920);          // 327,680 B
  float* d1   = (float*)(ws + 201113600);          // 1,048,576 B
  float* d2   = (float*)(ws + 202162176);          // 2,097,152 B

  hipLaunchKernelGGL(im2col_kernel, dim3(9600), dim3(256), 0, stream, x, A16);
  hipLaunchKernelGGL(c1trans_kernel, dim3(96), dim3(256), 0, stream,
                     conv1_w, wt1);
  hipLaunchKernelGGL(conv1_mfma_kernel, dim3(3200), dim3(256), 0, stream,
                     A16, wt1, conv1_b, ht);
  hipLaunchKernelGGL(wtrans_kernel, dim3(256, 4), dim3(256), 0, stream,
                     prim_w, wtp);
  hipLaunchKernelGGL(prim_mfma_kernel, dim3(2304), dim3(256), 0, stream,
                     ht, wtp, part);
  hipLaunchKernelGGL(rwprep_kernel, dim3(1152, 10), dim3(128), 0, stream,
                     route_w, rwh);
  hipLaunchKernelGGL(squash_kernel, dim3(2304), dim3(256), 0, stream,
                     part, prim_b, u16);
  hipLaunchKernelGGL(routing_kernel, dim3(5120), dim3(256), 0, stream,
                     u16, rwh, caps);
  hipLaunchKernelGGL(classes_kernel, dim3(2), dim3(256), 0, stream,
                     caps, out, d0);
  hipLaunchKernelGGL(fc_kernel, dim3(8, 8), dim3(256), 0, stream,
                     d0, dec_w1, dec_b1, d1, 512, 160, 0);
  hipLaunchKernelGGL(fc_kernel, dim3(16, 8), dim3(256), 0, stream,
                     d1, dec_w2, dec_b2, d2, 1024, 512, 0);
  hipLaunchKernelGGL(fc_kernel, dim3(13, 8), dim3(256), 0, stream,
                     d2, dec_w3, dec_b3, out + 5120, 784, 1024, 1);
}

// Round 5
// 1082.080 us; speedup vs baseline: 1.4519x; 1.4519x over previous
//
#include <hip/hip_runtime.h>
#include <math.h>

// ============================================================================
// CapsuleNet forward, round 18.
// R17 post-mortem: routing was NOT memory-reuse-bound -- it was SPILLING.
//   WRITE_SIZE 541MB = 413 B/thread = P[5][16] (320B) spilled to scratch;
//   FETCH 2.06GB = P re-read ~5x across routing iters. The fused priors'
//   fully-unrolled 5x8 load nest let the scheduler hoist up to ~320 regs of
//   loads -> scheduling-induced spill of the long-lived P array. Block
//   ordering was irrelevant (c-major/b-major identical counters).
// Fix (spill by construction impossible):
//   - routing at 512 thr/block: P[3][16] = 48 VGPRs (nk=3 for t<128 else 2;
//     1152 = 128*3 + 384*2). 8-wave reductions.
//   - sched_barrier(0) after each priors row + mid-row: caps transient load
//     pressure at ~40 regs -> total ~110 < 128 cap of launch_bounds(512,2).
// prim: R15 kept. conv1/im2col/wtrans/squash/rwprep/classes/fc unchanged.
// ============================================================================

typedef _Float16 f16;
typedef _Float16 f16x8 __attribute__((ext_vector_type(8)));
typedef _Float16 f16x4 __attribute__((ext_vector_type(4)));
typedef float f32x4 __attribute__((ext_vector_type(4)));

__device__ __forceinline__ void gl_lds16(const void* g, void* l) {
  __builtin_amdgcn_global_load_lds(
      (const __attribute__((address_space(1))) void*)g,
      (__attribute__((address_space(3))) void*)l, 16, 0, 0);
}

// --------- im2col: x[512,1,28,28] fp32 -> A16[m=204800][96] f16 ------------
__global__ void im2col_kernel(const float* __restrict__ x, f16* __restrict__ A)
{
  const int c = blockIdx.x * 256 + threadIdx.x;    // 2,457,600 exact
  const int m = c / 12, kc = c - m * 12;
  const int b = m / 400, rem = m - b * 400;
  const int oy = rem / 20, ox = rem - oy * 20;
  const float* xb = x + b * 784;
  f16x8 v;
#pragma unroll
  for (int j = 0; j < 8; ++j) {
    const int k = kc * 8 + j;
    float val = 0.f;
    if (k < 81) {
      const int ky = k / 9, kx = k - ky * 9;
      val = xb[(oy + ky) * 28 + ox + kx];
    }
    v[j] = (f16)val;
  }
  *(f16x8*)&A[(size_t)m * 96 + kc * 8] = v;
}

// --------- c1trans: conv1_w fp32 [256][81] -> wt1 f16 [256][96] (pad 0) ----
__global__ void c1trans_kernel(const float* __restrict__ w, f16* __restrict__ wt1)
{
  const int idx = blockIdx.x * 256 + threadIdx.x;  // 24576 exact
  const int oc = idx / 96, k = idx - oc * 96;
  wt1[idx] = (k < 81) ? (f16)w[oc * 81 + k] : (f16)0.f;
}

// --------- conv1 GEMM: ht[m][oc] = relu(A16 @ wt1^T + bias) ----------------
__global__ __launch_bounds__(256) void conv1_mfma_kernel(
    const f16* __restrict__ A, const f16* __restrict__ wt1,
    const float* __restrict__ bias, f16* __restrict__ ht)
{
  __shared__ f16 sm[8192];            // As[0..4096) | Bs[4096..8192)
  const int t = threadIdx.x;
  const int wv = t >> 6, lane = t & 63;
  const int id = blockIdx.x;
  const int mb = id >> 1, nb = id & 1;
  const int m0 = mb * 128, n0 = nb * 128;

  const int chunk = (lane & 3) ^ ((lane >> 3) & 3);
  long aoff[2], boff[2];
#pragma unroll
  for (int i = 0; i < 2; ++i) {
    const int r = wv * 32 + i * 16 + (lane >> 2);
    aoff[i] = (long)(m0 + r) * 192 + chunk * 16;
    boff[i] = (long)(n0 + r) * 192 + chunk * 16;
  }
  const char* ac = (const char*)A;
  const char* bc = (const char*)wt1;

  const int lrow = lane & 15, quad = lane >> 4;
  const int qx = quad ^ ((lrow >> 1) & 3);
  const int wm = wv & 1, wn = wv >> 1;
  f32x4 acc[4][4] = {};

  for (int s = 0; s < 3; ++s) {
    const long kstep = (long)s * 64;
    __syncthreads();
    {
      char* dA = (char*)sm + wv * 2048;
      char* dB = (char*)sm + 8192 + wv * 2048;
      gl_lds16(ac + aoff[0] + kstep, dA);
      gl_lds16(ac + aoff[1] + kstep, dA + 1024);
      gl_lds16(bc + boff[0] + kstep, dB);
      gl_lds16(bc + boff[1] + kstep, dB + 1024);
    }
    __syncthreads();
    const f16* As = sm;
    const f16* Bs = sm + 4096;
    f16x8 af[4], bf[4];
#pragma unroll
    for (int mt = 0; mt < 4; ++mt)
      af[mt] = *(const f16x8*)&As[(wm * 64 + mt * 16 + lrow) * 32 + qx * 8];
#pragma unroll
    for (int nt = 0; nt < 4; ++nt)
      bf[nt] = *(const f16x8*)&Bs[(wn * 64 + nt * 16 + lrow) * 32 + qx * 8];
#pragma unroll
    for (int mt = 0; mt < 4; ++mt)
#pragma unroll
      for (int nt = 0; nt < 4; ++nt)
        acc[mt][nt] = __builtin_amdgcn_mfma_f32_16x16x32_f16(
            af[mt], bf[nt], acc[mt][nt], 0, 0, 0);
  }

  // epilogue: ht[m*256 + oc] = relu(acc + bias[oc]) as f16 (NHWC, y/x in m)
#pragma unroll
  for (int nt = 0; nt < 4; ++nt) {
    const int n = n0 + wn * 64 + nt * 16 + lrow;          // col=lane&15
    const float bv = bias[n];
#pragma unroll
    for (int mt = 0; mt < 4; ++mt) {
      const int mbase = m0 + wm * 64 + mt * 16 + quad * 4; // row=quad*4+reg
#pragma unroll
      for (int rg = 0; rg < 4; ++rg)
        ht[(size_t)(mbase + rg) * 256 + n] =
            (f16)fmaxf(acc[mt][nt][rg] + bv, 0.f);
    }
  }
}

// --------- wtrans: prim_w fp32 [oc][ic][kykx] -> wt fp16 [oc][kykx][ic] ----
__global__ __launch_bounds__(256) void wtrans_kernel(
    const float* __restrict__ w, f16* __restrict__ wt)
{
  __shared__ float tile[64 * 83];
  const int oc = blockIdx.x;
  const int icq = blockIdx.y;
  const int t = threadIdx.x;
  const float* src = w + (size_t)oc * 20736 + (size_t)icq * 64 * 81;
  for (int idx = t; idx < 5184; idx += 256) {
    const int ici = idx / 81, kk = idx - ici * 81;
    tile[ici * 83 + kk] = src[idx];
  }
  __syncthreads();
  f16* dst = wt + (size_t)oc * 20736 + icq * 64;
  for (int idx = t; idx < 5184; idx += 256) {
    const int kk = idx >> 6, ici = idx & 63;
    dst[kk * 256 + ici] = (f16)tile[ici * 83 + kk];
  }
}

// ---------------- primary caps conv: MFMA implicit GEMM, split-K 8 ---------
// grid 2304 = 144 mb x 2 nb x 8 ks = exactly 3 rounds at 3 blocks/CU.
__global__ __launch_bounds__(256) void prim_mfma_kernel(
    const f16* __restrict__ ht, const f16* __restrict__ wt,
    f16* __restrict__ part)
{
  __shared__ f16 sm[24576];           // 48 KB: 3 buffers of [A 8KB | B 8KB]
  const int t = threadIdx.x;
  const int wv = t >> 6, lane = t & 63;
  const int id = blockIdx.x;
  const int ks = (id >> 3) & 7;                   // 8 K-slices
  const int nb = (id >> 6) & 1;
  const int mb = (id & 7) + 8 * (id >> 7);        // same-mb ids === mod 8
  const int m0 = mb * 128, n0 = nb * 128;

  const int chunk = (lane & 3) ^ ((lane >> 3) & 3);
  long aoff[2], boff[2];
#pragma unroll
  for (int i = 0; i < 2; ++i) {
    const int r = wv * 32 + i * 16 + (lane >> 2);
    const int m = m0 + r;
    const int b = m / 36, pos = m - b * 36;
    const int oy = pos / 6, ox = pos - oy * 6;
    aoff[i] = (long)(((b * 20 + 2 * oy) * 20 + 2 * ox) * 256) * 2 + chunk * 16;
    boff[i] = (long)(n0 + r) * 41472 + chunk * 16;   // oc*81*256*2
  }
  const char* htc = (const char*)ht;
  const char* wtc = (const char*)wt;

  const int lrow = lane & 15, quad = lane >> 4;
  const int qx = quad ^ ((lrow >> 1) & 3);
  const int wm = wv & 1, wn = wv >> 1;
  f32x4 acc[4][4] = {};

  const int s0 = ks * 81;             // 81 stages per slice

#define STAGE(S, BUFB)                                                        \
  {                                                                           \
    const int kykx = (S) >> 3, icb = (S) & 7;                                 \
    const int ky = kykx / 9, kx = kykx - ky * 9;                              \
    const long astep = (long)((((ky * 20 + kx) * 256) + icb * 32) * 2);       \
    const long bstep = (long)(((kykx * 256) + icb * 32) * 2);                 \
    char* dA = (char*)sm + (BUFB) + wv * 2048;                                \
    char* dB = (char*)sm + (BUFB) + 8192 + wv * 2048;                         \
    gl_lds16(htc + aoff[0] + astep, dA);                                      \
    gl_lds16(htc + aoff[1] + astep, dA + 1024);                               \
    gl_lds16(wtc + boff[0] + bstep, dB);                                      \
    gl_lds16(wtc + boff[1] + bstep, dB + 1024);                               \
  }

#define CONSUME(BUFI)                                                         \
  {                                                                           \
    const f16* As = sm + (BUFI);                                              \
    const f16* Bs = sm + (BUFI) + 4096;                                       \
    f16x8 af[4], bf[4];                                                       \
    _Pragma("unroll") for (int mt = 0; mt < 4; ++mt)                          \
        af[mt] = *(const f16x8*)&As[(wm * 64 + mt * 16 + lrow) * 32 + qx * 8];\
    _Pragma("unroll") for (int nt = 0; nt < 4; ++nt)                          \
        bf[nt] = *(const f16x8*)&Bs[(wn * 64 + nt * 16 + lrow) * 32 + qx * 8];\
    _Pragma("unroll") for (int mt = 0; mt < 4; ++mt)                          \
        _Pragma("unroll") for (int nt = 0; nt < 4; ++nt)                      \
            acc[mt][nt] = __builtin_amdgcn_mfma_f32_16x16x32_f16(             \
                af[mt], bf[nt], acc[mt][nt], 0, 0, 0);                        \
  }

  // depth-2 pipeline, 3 buffers (byte offsets 0 / 16384 / 32768)
  STAGE(s0, 0);
  STAGE(s0 + 1, 16384);
  int bS = 32768;                     // stage target:   (K+2)%3
  int bC = 0;                         // consume buffer:  K   %3
  for (int K = 0; K < 79; ++K) {
    asm volatile("s_waitcnt vmcnt(4)" ::: "memory");  // own stage-K writes done
    __builtin_amdgcn_s_barrier();                     // publish to all waves
    asm volatile("" ::: "memory");
    STAGE(s0 + K + 2, bS);
    __builtin_amdgcn_s_setprio(1);
    CONSUME(bC >> 1);
    __builtin_amdgcn_s_setprio(0);
    bS += 16384; if (bS == 49152) bS = 0;
    bC += 16384; if (bC == 49152) bC = 0;
  }
  // K = 79: stages 79,80 in flight; wait 79 (4 newest = stage 80 may fly)
  asm volatile("s_waitcnt vmcnt(4)" ::: "memory");
  __builtin_amdgcn_s_barrier();
  asm volatile("" ::: "memory");
  __builtin_amdgcn_s_setprio(1);
  CONSUME(bC >> 1);
  __builtin_amdgcn_s_setprio(0);
  bC += 16384; if (bC == 49152) bC = 0;
  // K = 80: wait everything
  asm volatile("s_waitcnt vmcnt(0)" ::: "memory");
  __builtin_amdgcn_s_barrier();
  asm volatile("" ::: "memory");
  CONSUME(bC >> 1);
#undef STAGE
#undef CONSUME

  // epilogue: f16 partials, 8 slices of [18432][256], permuted np layout
  f16* pp = part + (size_t)ks * 4718592;
#pragma unroll
  for (int mt = 0; mt < 4; ++mt) {
    const int mbase = m0 + wm * 64 + mt * 16 + quad * 4;
#pragma unroll
    for (int nt = 0; nt < 4; ++nt) {
      const int n = n0 + wn * 64 + nt * 16 + lrow;
      const int np = (n & 31) * 8 + (n >> 5);
#pragma unroll
      for (int rg = 0; rg < 4; ++rg)
        pp[(size_t)(mbase + rg) * 256 + np] = (f16)acc[mt][nt][rg];
    }
  }
}

// --------- split-K(8) reduce + bias + squash -> u16[512][rs=pos*32+cc][8] --
__global__ void squash_kernel(const f16* __restrict__ part,
                              const float* __restrict__ bias,
                              f16* __restrict__ u16)
{
  const int tid = blockIdx.x * 256 + threadIdx.x;   // (b*36+pos)*32 + cc
  if (tid >= 512 * 36 * 32) return;
  const int cc = tid & 31;
  const int row = tid >> 5;                         // b*36 + pos
  const int b = row / 36;
  const int pos = row - b * 36;
  const f16* p = part + (size_t)row * 256 + cc * 8;
  float v[8] = {};
#pragma unroll
  for (int ksl = 0; ksl < 8; ++ksl) {
    const f16x8 a = *(const f16x8*)(p + (size_t)ksl * 4718592);
#pragma unroll
    for (int i = 0; i < 8; ++i) v[i] += (float)a[i];
  }
  float sq = 0.f;
#pragma unroll
  for (int i = 0; i < 8; ++i) {
    v[i] += bias[i * 32 + cc];
    sq = fmaf(v[i], v[i], sq);
  }
  const float scale = sq / ((1.f + sq) * sqrtf(sq));
  f16x8 st;
#pragma unroll
  for (int i = 0; i < 8; ++i) st[i] = (f16)(v[i] * scale);
  *(f16x8*)&u16[(size_t)(b * 1152 + pos * 32 + cc) * 8] = st;   // contiguous
}

// --------- rwprep: route_w f32 [c][r_true][8][16] -> rwh f16 [c][rs][8][16] -
// storage order rs = pos*32+cc  <->  r_true = cc*36+pos
__global__ void rwprep_kernel(const float* __restrict__ rw, f16* __restrict__ rwh)
{
  const int rs = blockIdx.x;            // [0,1152)
  const int c  = blockIdx.y;            // [0,10)
  const int t  = threadIdx.x;           // [0,128) = k*16+o
  const int pos = rs >> 5, cc = rs & 31;
  const int r_true = cc * 36 + pos;
  const float v = rw[(size_t)(c * 1152 + r_true) * 128 + t];
  rwh[(size_t)(c * 1152 + rs) * 128 + t] = (f16)v;
}

// ---------------- FUSED priors + dynamic routing, one block per (b,c) ------
// 512 threads: P[3][16]=48 regs (nk=3 for t<128, else 2; 1152=128*3+384*2).
// sched_barrier fences stop the load-nest hoisting that spilled R16/R17.
__device__ __forceinline__ float wave_sum(float v) {
#pragma unroll
  for (int off = 32; off > 0; off >>= 1) v += __shfl_xor(v, off);
  return v;
}
__device__ __forceinline__ float wave_max(float v) {
#pragma unroll
  for (int off = 32; off > 0; off >>= 1) v = fmaxf(v, __shfl_xor(v, off));
  return v;
}

__global__ __launch_bounds__(512, 2) void routing_kernel(
    const f16* __restrict__ u16, const f16* __restrict__ rwh,
    float* __restrict__ caps)
{
  const int c = blockIdx.x % 10;
  const int b = blockIdx.x / 10;
  const int t = threadIdx.x;            // 0..511
  const int wid = t >> 6;               // 0..7
  const int lane = t & 63;
  __shared__ float xred[8 * 17];

  float P[3][16];
  float lg[3];
  const int nk = (t < 128) ? 3 : 2;
#pragma unroll
  for (int k = 0; k < 3; ++k)
#pragma unroll
    for (int o = 0; o < 16; ++o) P[k][o] = 0.f;

  // ---- fused priors: P[k][o] = sum_kk u[b,rs,kk] * rwh[c,rs,kk,o] ----
  const f16* ub = u16 + (size_t)b * 9216;           // b*1152*8
  const f16* wb = rwh + (size_t)c * 147456;         // c*1152*128

#define PRIORS_ROW(K)                                                         \
  {                                                                           \
    const int rs = t + ((K) << 9);                                            \
    const f16x8 uv = *(const f16x8*)&ub[(size_t)rs * 8];                      \
    float uf[8];                                                              \
    _Pragma("unroll") for (int i = 0; i < 8; ++i) uf[i] = (float)uv[i];       \
    const f16* wr = wb + (size_t)rs * 128;                                    \
    _Pragma("unroll") for (int kk = 0; kk < 8; ++kk) {                        \
      const f16x8 w0 = *(const f16x8*)&wr[kk * 16];                           \
      const f16x8 w1 = *(const f16x8*)&wr[kk * 16 + 8];                       \
      _Pragma("unroll") for (int o = 0; o < 8; ++o) {                         \
        P[K][o]     = fmaf(uf[kk], (float)w0[o], P[K][o]);                    \
        P[K][o + 8] = fmaf(uf[kk], (float)w1[o], P[K][o + 8]);                \
      }                                                                       \
      if (kk == 3) __builtin_amdgcn_sched_barrier(0);                         \
    }                                                                         \
  }

  PRIORS_ROW(0);
  __builtin_amdgcn_sched_barrier(0);
  PRIORS_ROW(1);
  __builtin_amdgcn_sched_barrier(0);
  if (t < 128) PRIORS_ROW(2);
  __builtin_amdgcn_sched_barrier(0);
#undef PRIORS_ROW

  float v[16];
  {
    float sq = 0.f;
#pragma unroll
    for (int o = 0; o < 16; ++o) {
      float p = P[0][o] + P[1][o] + P[2][o];   // P[2]=0 for inactive threads
      p = wave_sum(p);
      if (lane == 0) xred[wid * 17 + o] = p;
      v[o] = 0.f;
    }
    __syncthreads();
#pragma unroll
    for (int o = 0; o < 16; ++o) {
      float s = 0.f;
#pragma unroll
      for (int w = 0; w < 8; ++w) s += xred[w * 17 + o];
      s *= (1.f / 1152.f);
      v[o] = s;
      sq = fmaf(s, s, sq);
    }
    const float scale = sq / ((1.f + sq) * sqrtf(sq));
#pragma unroll
    for (int o = 0; o < 16; ++o) v[o] *= scale;
    __syncthreads();
  }
#pragma unroll
  for (int k = 0; k < 3; ++k) {
    float a = 0.f;
#pragma unroll
    for (int o = 0; o < 16; ++o) a = fmaf(P[k][o], v[o], a);
    lg[k] = a;                                // lg[2]=0 for inactive threads
  }

  for (int it = 1; it < 3; ++it) {
    float m = -1e30f;
#pragma unroll
    for (int k = 0; k < 3; ++k) if (k < nk) m = fmaxf(m, lg[k]);
    m = wave_max(m);
    if (lane == 0) xred[wid * 17 + 16] = m;
    __syncthreads();
    float mx = xred[16];
#pragma unroll
    for (int w = 1; w < 8; ++w) mx = fmaxf(mx, xred[w * 17 + 16]);
    __syncthreads();
    float e[3];
#pragma unroll
    for (int k = 0; k < 3; ++k) e[k] = (k < nk) ? expf(lg[k] - mx) : 0.f;
    float pS = e[0] + e[1] + e[2];
    pS = wave_sum(pS);
    if (lane == 0) xred[wid * 17 + 16] = pS;
#pragma unroll
    for (int o = 0; o < 16; ++o) {
      float p = 0.f;
#pragma unroll
      for (int k = 0; k < 3; ++k) p = fmaf(e[k], P[k][o], p);
      p = wave_sum(p);
      if (lane == 0) xred[wid * 17 + o] = p;
    }
    __syncthreads();
    float S = 0.f;
#pragma unroll
    for (int w = 0; w < 8; ++w) S += xred[w * 17 + 16];
    const float inv = 1.f / S;
    float sq = 0.f;
#pragma unroll
    for (int o = 0; o < 16; ++o) {
      float s = 0.f;
#pragma unroll
      for (int w = 0; w < 8; ++w) s += xred[w * 17 + o];
      s *= inv;
      v[o] = s;
      sq = fmaf(s, s, sq);
    }
    const float scale = sq / ((1.f + sq) * sqrtf(sq));
#pragma unroll
    for (int o = 0; o < 16; ++o) v[o] *= scale;
    __syncthreads();
    if (it < 2) {
#pragma unroll
      for (int k = 0; k < 3; ++k) {
        float a = 0.f;
#pragma unroll
        for (int o = 0; o < 16; ++o) a = fmaf(P[k][o], v[o], a);
        lg[k] += a;
      }
    }
  }
  if (t == 0) {
    float* cp = &caps[(b * 10 + c) * 16];
#pragma unroll
    for (int o = 0; o < 16; ++o) cp[o] = v[o];
  }
}

// --------- classes softmax + argmax one-hot mask ---------------------------
__global__ void classes_kernel(const float* __restrict__ caps,
                               float* __restrict__ out_classes,
                               float* __restrict__ d0)
{
  const int b = blockIdx.x * 256 + threadIdx.x;
  if (b >= 512) return;
  float nrm[10];
#pragma unroll
  for (int cc = 0; cc < 10; ++cc) {
    float sq = 0.f;
#pragma unroll
    for (int o = 0; o < 16; ++o) {
      const float vv = caps[(b * 10 + cc) * 16 + o];
      sq = fmaf(vv, vv, sq);
    }
    nrm[cc] = sqrtf(sq);
  }
  float mx = nrm[0]; int cs = 0;
#pragma unroll
  for (int cc = 1; cc < 10; ++cc)
    if (nrm[cc] > mx) { mx = nrm[cc]; cs = cc; }
  float e[10], ssum = 0.f;
#pragma unroll
  for (int cc = 0; cc < 10; ++cc) { e[cc] = expf(nrm[cc] - mx); ssum += e[cc]; }
  const float inv = 1.f / ssum;
#pragma unroll
  for (int cc = 0; cc < 10; ++cc) out_classes[b * 10 + cc] = e[cc] * inv;
#pragma unroll
  for (int cc = 0; cc < 10; ++cc)
#pragma unroll
    for (int o = 0; o < 16; ++o)
      d0[b * 160 + cc * 16 + o] = (cc == cs) ? caps[(b * 10 + cc) * 16 + o] : 0.f;
}

// --------- decoder GEMM: C[M,N] = act(A[M,K] @ W[N,K]^T + bias) ------------
__global__ __launch_bounds__(256, 2) void fc_kernel(
    const float* __restrict__ A, const float* __restrict__ W,
    const float* __restrict__ bias, float* __restrict__ C,
    int N, int K, int act)
{
  __shared__ float As[64][17];
  __shared__ float Ws[64][17];
  const int t = threadIdx.x;
  const int tm = t >> 4, tn = t & 15;
  const int m0 = blockIdx.y << 6, n0 = blockIdx.x << 6;
  const int lr = t >> 2, lq = (t & 3) << 2;
  float acc[4][4] = {};
  for (int k0 = 0; k0 < K; k0 += 16) {
    const float4 av = *(const float4*)&A[(m0 + lr) * K + k0 + lq];
    float4 wv = make_float4(0.f, 0.f, 0.f, 0.f);
    const int wn = n0 + lr;
    if (wn < N) wv = *(const float4*)&W[wn * K + k0 + lq];
    __syncthreads();
    As[lr][lq+0] = av.x; As[lr][lq+1] = av.y; As[lr][lq+2] = av.z; As[lr][lq+3] = av.w;
    Ws[lr][lq+0] = wv.x; Ws[lr][lq+1] = wv.y; Ws[lr][lq+2] = wv.z; Ws[lr][lq+3] = wv.w;
    __syncthreads();
#pragma unroll
    for (int kk = 0; kk < 16; ++kk) {
      float a[4], w[4];
#pragma unroll
      for (int i = 0; i < 4; ++i) a[i] = As[tm * 4 + i][kk];
#pragma unroll
      for (int j = 0; j < 4; ++j) w[j] = Ws[tn * 4 + j][kk];
#pragma unroll
      for (int i = 0; i < 4; ++i)
#pragma unroll
        for (int j = 0; j < 4; ++j) acc[i][j] = fmaf(a[i], w[j], acc[i][j]);
    }
  }
#pragma unroll
  for (int i = 0; i < 4; ++i) {
    const int m = m0 + tm * 4 + i;
#pragma unroll
    for (int j = 0; j < 4; ++j) {
      const int n = n0 + tn * 4 + j;
      if (n < N) {
        float vv = acc[i][j] + bias[n];
        vv = act ? (1.f / (1.f + expf(-vv))) : fmaxf(vv, 0.f);
        C[m * N + n] = vv;
      }
    }
  }
}

// ============================================================================
extern "C" void kernel_launch(void* const* d_in, const int* in_sizes, int n_in,
                              void* d_out, int out_size, void* d_ws, size_t ws_size,
                              hipStream_t stream)
{
  const float* x       = (const float*)d_in[0];
  const float* conv1_w = (const float*)d_in[1];
  const float* conv1_b = (const float*)d_in[2];
  const float* prim_w  = (const float*)d_in[3];
  const float* prim_b  = (const float*)d_in[4];
  const float* route_w = (const float*)d_in[5];
  const float* dec_w1  = (const float*)d_in[6];
  const float* dec_b1  = (const float*)d_in[7];
  const float* dec_w2  = (const float*)d_in[8];
  const float* dec_b2  = (const float*)d_in[9];
  const float* dec_w3  = (const float*)d_in[10];
  const float* dec_b3  = (const float*)d_in[11];
  float* out = (float*)d_out;

  char* ws = (char*)d_ws;
  f16*   ht   = (f16*)(ws);                        // 104,857,600 B
  f16*   wtp  = (f16*)(ws + 104857600);            //  10,616,832 B
  f16*   part = (f16*)(ws + 115474432);            //  75,497,472 B (8 f16 slices)
  f16*   A16  = (f16*)(ws + 115474432);            //  39,321,600 B (overlays
                                                   //  part; dead before prim)
  f16*   wt1  = (f16*)(ws + 190971904);            //      49,152 B
  f16*   u16  = (f16*)(ws + 191021056);            //   9,437,184 B
  f16*   rwh  = (f16*)(ws);                        //   2,949,120 B (overlays
                                                   //  ht, dead after prim)
  float* caps = (float*)(ws + 200458240);          // 327,680 B
  float* d0   = (float*)(ws + 200785920);          // 327,680 B
  float* d1   = (float*)(ws + 201113600);          // 1,048,576 B
  float* d2   = (float*)(ws + 202162176);          // 2,097,152 B

  hipLaunchKernelGGL(im2col_kernel, dim3(9600), dim3(256), 0, stream, x, A16);
  hipLaunchKernelGGL(c1trans_kernel, dim3(96), dim3(256), 0, stream,
                     conv1_w, wt1);
  hipLaunchKernelGGL(conv1_mfma_kernel, dim3(3200), dim3(256), 0, stream,
                     A16, wt1, conv1_b, ht);
  hipLaunchKernelGGL(wtrans_kernel, dim3(256, 4), dim3(256), 0, stream,
                     prim_w, wtp);
  hipLaunchKernelGGL(prim_mfma_kernel, dim3(2304), dim3(256), 0, stream,
                     ht, wtp, part);
  hipLaunchKernelGGL(rwprep_kernel, dim3(1152, 10), dim3(128), 0, stream,
                     route_w, rwh);
  hipLaunchKernelGGL(squash_kernel, dim3(2304), dim3(256), 0, stream,
                     part, prim_b, u16);
  hipLaunchKernelGGL(routing_kernel, dim3(5120), dim3(512), 0, stream,
                     u16, rwh, caps);
  hipLaunchKernelGGL(classes_kernel, dim3(2), dim3(256), 0, stream,
                     caps, out, d0);
  hipLaunchKernelGGL(fc_kernel, dim3(8, 8), dim3(256), 0, stream,
                     d0, dec_w1, dec_b1, d1, 512, 160, 0);
  hipLaunchKernelGGL(fc_kernel, dim3(16, 8), dim3(256), 0, stream,
                     d1, dec_w2, dec_b2, d2, 1024, 512, 0);
  hipLaunchKernelGGL(fc_kernel, dim3(13, 8), dim3(256), 0, stream,
                     d2, dec_w3, dec_b3, out + 5120, 784, 1024, 1);
}

// Round 6
// 969.615 us; speedup vs baseline: 1.6203x; 1.1160x over previous
//
#include <hip/hip_runtime.h>
#include <math.h>

// ============================================================================
// CapsuleNet forward, round 19.
// R18 post-mortem: routing spill fixed (WRITE 541MB->320KB) but dur still
//   501us, all pipes idle => transaction-bound: lane stride in the priors
//   w-read was 256B (rs = t + k*512, row-major rwh[..rs][kk,o]) -> every
//   f16x8 wave-load = 64 cache-line transactions. ~22K transactions/block
//   ~60K cyc -> 20 blocks/CU / 2 resident = 500us. Arithmetic closes.
// Fix: TRANSPOSE rwh to [c][o][rs][kk] (kk innermost). For fixed o, lane t
//   reads 8 contiguous f16 -> 16B/lane, 1KB/wave, 1 transaction. P[k][o] is
//   then one 8-wide dot: v_dot2_f32_f16 x4 (__builtin_amdgcn_fdot2, fma
//   fallback). rwprep rewritten with 33KB LDS tile: coalesced read of rw and
//   coalesced f16 writes of the transposed layout.
// prim: R15 kept. conv1/im2col/wtrans/squash/classes/fc unchanged.
// ============================================================================

typedef _Float16 f16;
typedef _Float16 f16x8 __attribute__((ext_vector_type(8)));
typedef _Float16 f16x4 __attribute__((ext_vector_type(4)));
typedef _Float16 f16x2 __attribute__((ext_vector_type(2)));
typedef float f32x4 __attribute__((ext_vector_type(4)));

__device__ __forceinline__ void gl_lds16(const void* g, void* l) {
  __builtin_amdgcn_global_load_lds(
      (const __attribute__((address_space(1))) void*)g,
      (__attribute__((address_space(3))) void*)l, 16, 0, 0);
}

__device__ __forceinline__ float dot8(f16x8 a, f16x8 b) {
#if __has_builtin(__builtin_amdgcn_fdot2)
  float s = 0.f;
#pragma unroll
  for (int j = 0; j < 4; ++j) {
    f16x2 av, bv;
    av[0] = a[2 * j]; av[1] = a[2 * j + 1];
    bv[0] = b[2 * j]; bv[1] = b[2 * j + 1];
    s = __builtin_amdgcn_fdot2(av, bv, s, false);
  }
  return s;
#else
  float s = 0.f;
#pragma unroll
  for (int i = 0; i < 8; ++i) s = fmaf((float)a[i], (float)b[i], s);
  return s;
#endif
}

// --------- im2col: x[512,1,28,28] fp32 -> A16[m=204800][96] f16 ------------
__global__ void im2col_kernel(const float* __restrict__ x, f16* __restrict__ A)
{
  const int c = blockIdx.x * 256 + threadIdx.x;    // 2,457,600 exact
  const int m = c / 12, kc = c - m * 12;
  const int b = m / 400, rem = m - b * 400;
  const int oy = rem / 20, ox = rem - oy * 20;
  const float* xb = x + b * 784;
  f16x8 v;
#pragma unroll
  for (int j = 0; j < 8; ++j) {
    const int k = kc * 8 + j;
    float val = 0.f;
    if (k < 81) {
      const int ky = k / 9, kx = k - ky * 9;
      val = xb[(oy + ky) * 28 + ox + kx];
    }
    v[j] = (f16)val;
  }
  *(f16x8*)&A[(size_t)m * 96 + kc * 8] = v;
}

// --------- c1trans: conv1_w fp32 [256][81] -> wt1 f16 [256][96] (pad 0) ----
__global__ void c1trans_kernel(const float* __restrict__ w, f16* __restrict__ wt1)
{
  const int idx = blockIdx.x * 256 + threadIdx.x;  // 24576 exact
  const int oc = idx / 96, k = idx - oc * 96;
  wt1[idx] = (k < 81) ? (f16)w[oc * 81 + k] : (f16)0.f;
}

// --------- conv1 GEMM: ht[m][oc] = relu(A16 @ wt1^T + bias) ----------------
__global__ __launch_bounds__(256) void conv1_mfma_kernel(
    const f16* __restrict__ A, const f16* __restrict__ wt1,
    const float* __restrict__ bias, f16* __restrict__ ht)
{
  __shared__ f16 sm[8192];            // As[0..4096) | Bs[4096..8192)
  const int t = threadIdx.x;
  const int wv = t >> 6, lane = t & 63;
  const int id = blockIdx.x;
  const int mb = id >> 1, nb = id & 1;
  const int m0 = mb * 128, n0 = nb * 128;

  const int chunk = (lane & 3) ^ ((lane >> 3) & 3);
  long aoff[2], boff[2];
#pragma unroll
  for (int i = 0; i < 2; ++i) {
    const int r = wv * 32 + i * 16 + (lane >> 2);
    aoff[i] = (long)(m0 + r) * 192 + chunk * 16;
    boff[i] = (long)(n0 + r) * 192 + chunk * 16;
  }
  const char* ac = (const char*)A;
  const char* bc = (const char*)wt1;

  const int lrow = lane & 15, quad = lane >> 4;
  const int qx = quad ^ ((lrow >> 1) & 3);
  const int wm = wv & 1, wn = wv >> 1;
  f32x4 acc[4][4] = {};

  for (int s = 0; s < 3; ++s) {
    const long kstep = (long)s * 64;
    __syncthreads();
    {
      char* dA = (char*)sm + wv * 2048;
      char* dB = (char*)sm + 8192 + wv * 2048;
      gl_lds16(ac + aoff[0] + kstep, dA);
      gl_lds16(ac + aoff[1] + kstep, dA + 1024);
      gl_lds16(bc + boff[0] + kstep, dB);
      gl_lds16(bc + boff[1] + kstep, dB + 1024);
    }
    __syncthreads();
    const f16* As = sm;
    const f16* Bs = sm + 4096;
    f16x8 af[4], bf[4];
#pragma unroll
    for (int mt = 0; mt < 4; ++mt)
      af[mt] = *(const f16x8*)&As[(wm * 64 + mt * 16 + lrow) * 32 + qx * 8];
#pragma unroll
    for (int nt = 0; nt < 4; ++nt)
      bf[nt] = *(const f16x8*)&Bs[(wn * 64 + nt * 16 + lrow) * 32 + qx * 8];
#pragma unroll
    for (int mt = 0; mt < 4; ++mt)
#pragma unroll
      for (int nt = 0; nt < 4; ++nt)
        acc[mt][nt] = __builtin_amdgcn_mfma_f32_16x16x32_f16(
            af[mt], bf[nt], acc[mt][nt], 0, 0, 0);
  }

  // epilogue: ht[m*256 + oc] = relu(acc + bias[oc]) as f16 (NHWC, y/x in m)
#pragma unroll
  for (int nt = 0; nt < 4; ++nt) {
    const int n = n0 + wn * 64 + nt * 16 + lrow;          // col=lane&15
    const float bv = bias[n];
#pragma unroll
    for (int mt = 0; mt < 4; ++mt) {
      const int mbase = m0 + wm * 64 + mt * 16 + quad * 4; // row=quad*4+reg
#pragma unroll
      for (int rg = 0; rg < 4; ++rg)
        ht[(size_t)(mbase + rg) * 256 + n] =
            (f16)fmaxf(acc[mt][nt][rg] + bv, 0.f);
    }
  }
}

// --------- wtrans: prim_w fp32 [oc][ic][kykx] -> wt fp16 [oc][kykx][ic] ----
__global__ __launch_bounds__(256) void wtrans_kernel(
    const float* __restrict__ w, f16* __restrict__ wt)
{
  __shared__ float tile[64 * 83];
  const int oc = blockIdx.x;
  const int icq = blockIdx.y;
  const int t = threadIdx.x;
  const float* src = w + (size_t)oc * 20736 + (size_t)icq * 64 * 81;
  for (int idx = t; idx < 5184; idx += 256) {
    const int ici = idx / 81, kk = idx - ici * 81;
    tile[ici * 83 + kk] = src[idx];
  }
  __syncthreads();
  f16* dst = wt + (size_t)oc * 20736 + icq * 64;
  for (int idx = t; idx < 5184; idx += 256) {
    const int kk = idx >> 6, ici = idx & 63;
    dst[kk * 256 + ici] = (f16)tile[ici * 83 + kk];
  }
}

// ---------------- primary caps conv: MFMA implicit GEMM, split-K 8 ---------
// grid 2304 = 144 mb x 2 nb x 8 ks = exactly 3 rounds at 3 blocks/CU.
__global__ __launch_bounds__(256) void prim_mfma_kernel(
    const f16* __restrict__ ht, const f16* __restrict__ wt,
    f16* __restrict__ part)
{
  __shared__ f16 sm[24576];           // 48 KB: 3 buffers of [A 8KB | B 8KB]
  const int t = threadIdx.x;
  const int wv = t >> 6, lane = t & 63;
  const int id = blockIdx.x;
  const int ks = (id >> 3) & 7;                   // 8 K-slices
  const int nb = (id >> 6) & 1;
  const int mb = (id & 7) + 8 * (id >> 7);        // same-mb ids === mod 8
  const int m0 = mb * 128, n0 = nb * 128;

  const int chunk = (lane & 3) ^ ((lane >> 3) & 3);
  long aoff[2], boff[2];
#pragma unroll
  for (int i = 0; i < 2; ++i) {
    const int r = wv * 32 + i * 16 + (lane >> 2);
    const int m = m0 + r;
    const int b = m / 36, pos = m - b * 36;
    const int oy = pos / 6, ox = pos - oy * 6;
    aoff[i] = (long)(((b * 20 + 2 * oy) * 20 + 2 * ox) * 256) * 2 + chunk * 16;
    boff[i] = (long)(n0 + r) * 41472 + chunk * 16;   // oc*81*256*2
  }
  const char* htc = (const char*)ht;
  const char* wtc = (const char*)wt;

  const int lrow = lane & 15, quad = lane >> 4;
  const int qx = quad ^ ((lrow >> 1) & 3);
  const int wm = wv & 1, wn = wv >> 1;
  f32x4 acc[4][4] = {};

  const int s0 = ks * 81;             // 81 stages per slice

#define STAGE(S, BUFB)                                                        \
  {                                                                           \
    const int kykx = (S) >> 3, icb = (S) & 7;                                 \
    const int ky = kykx / 9, kx = kykx - ky * 9;                              \
    const long astep = (long)((((ky * 20 + kx) * 256) + icb * 32) * 2);       \
    const long bstep = (long)(((kykx * 256) + icb * 32) * 2);                 \
    char* dA = (char*)sm + (BUFB) + wv * 2048;                                \
    char* dB = (char*)sm + (BUFB) + 8192 + wv * 2048;                         \
    gl_lds16(htc + aoff[0] + astep, dA);                                      \
    gl_lds16(htc + aoff[1] + astep, dA + 1024);                               \
    gl_lds16(wtc + boff[0] + bstep, dB);                                      \
    gl_lds16(wtc + boff[1] + bstep, dB + 1024);                               \
  }

#define CONSUME(BUFI)                                                         \
  {                                                                           \
    const f16* As = sm + (BUFI);                                              \
    const f16* Bs = sm + (BUFI) + 4096;                                       \
    f16x8 af[4], bf[4];                                                       \
    _Pragma("unroll") for (int mt = 0; mt < 4; ++mt)                          \
        af[mt] = *(const f16x8*)&As[(wm * 64 + mt * 16 + lrow) * 32 + qx * 8];\
    _Pragma("unroll") for (int nt = 0; nt < 4; ++nt)                          \
        bf[nt] = *(const f16x8*)&Bs[(wn * 64 + nt * 16 + lrow) * 32 + qx * 8];\
    _Pragma("unroll") for (int mt = 0; mt < 4; ++mt)                          \
        _Pragma("unroll") for (int nt = 0; nt < 4; ++nt)                      \
            acc[mt][nt] = __builtin_amdgcn_mfma_f32_16x16x32_f16(             \
                af[mt], bf[nt], acc[mt][nt], 0, 0, 0);                        \
  }

  // depth-2 pipeline, 3 buffers (byte offsets 0 / 16384 / 32768)
  STAGE(s0, 0);
  STAGE(s0 + 1, 16384);
  int bS = 32768;                     // stage target:   (K+2)%3
  int bC = 0;                         // consume buffer:  K   %3
  for (int K = 0; K < 79; ++K) {
    asm volatile("s_waitcnt vmcnt(4)" ::: "memory");  // own stage-K writes done
    __builtin_amdgcn_s_barrier();                     // publish to all waves
    asm volatile("" ::: "memory");
    STAGE(s0 + K + 2, bS);
    __builtin_amdgcn_s_setprio(1);
    CONSUME(bC >> 1);
    __builtin_amdgcn_s_setprio(0);
    bS += 16384; if (bS == 49152) bS = 0;
    bC += 16384; if (bC == 49152) bC = 0;
  }
  // K = 79: stages 79,80 in flight; wait 79 (4 newest = stage 80 may fly)
  asm volatile("s_waitcnt vmcnt(4)" ::: "memory");
  __builtin_amdgcn_s_barrier();
  asm volatile("" ::: "memory");
  __builtin_amdgcn_s_setprio(1);
  CONSUME(bC >> 1);
  __builtin_amdgcn_s_setprio(0);
  bC += 16384; if (bC == 49152) bC = 0;
  // K = 80: wait everything
  asm volatile("s_waitcnt vmcnt(0)" ::: "memory");
  __builtin_amdgcn_s_barrier();
  asm volatile("" ::: "memory");
  CONSUME(bC >> 1);
#undef STAGE
#undef CONSUME

  // epilogue: f16 partials, 8 slices of [18432][256], permuted np layout
  f16* pp = part + (size_t)ks * 4718592;
#pragma unroll
  for (int mt = 0; mt < 4; ++mt) {
    const int mbase = m0 + wm * 64 + mt * 16 + quad * 4;
#pragma unroll
    for (int nt = 0; nt < 4; ++nt) {
      const int n = n0 + wn * 64 + nt * 16 + lrow;
      const int np = (n & 31) * 8 + (n >> 5);
#pragma unroll
      for (int rg = 0; rg < 4; ++rg)
        pp[(size_t)(mbase + rg) * 256 + np] = (f16)acc[mt][nt][rg];
    }
  }
}

// --------- split-K(8) reduce + bias + squash -> u16[512][rs=pos*32+cc][8] --
__global__ void squash_kernel(const f16* __restrict__ part,
                              const float* __restrict__ bias,
                              f16* __restrict__ u16)
{
  const int tid = blockIdx.x * 256 + threadIdx.x;   // (b*36+pos)*32 + cc
  if (tid >= 512 * 36 * 32) return;
  const int cc = tid & 31;
  const int row = tid >> 5;                         // b*36 + pos
  const int b = row / 36;
  const int pos = row - b * 36;
  const f16* p = part + (size_t)row * 256 + cc * 8;
  float v[8] = {};
#pragma unroll
  for (int ksl = 0; ksl < 8; ++ksl) {
    const f16x8 a = *(const f16x8*)(p + (size_t)ksl * 4718592);
#pragma unroll
    for (int i = 0; i < 8; ++i) v[i] += (float)a[i];
  }
  float sq = 0.f;
#pragma unroll
  for (int i = 0; i < 8; ++i) {
    v[i] += bias[i * 32 + cc];
    sq = fmaf(v[i], v[i], sq);
  }
  const float scale = sq / ((1.f + sq) * sqrtf(sq));
  f16x8 st;
#pragma unroll
  for (int i = 0; i < 8; ++i) st[i] = (f16)(v[i] * scale);
  *(f16x8*)&u16[(size_t)(b * 1152 + pos * 32 + cc) * 8] = st;   // contiguous
}

// --------- rwprep: route_w f32 [c][r_true][8][16] -> rwh f16 [c][o][rs][kk] -
// transposed so routing's per-o wave-loads are lane-contiguous (16B/lane).
// block = (rs-chunk of 64, c); LDS tile keeps both sides coalesced.
__global__ __launch_bounds__(256) void rwprep_kernel(
    const float* __restrict__ rw, f16* __restrict__ rwh)
{
  __shared__ float tile[64][129];
  const int rs0 = blockIdx.x * 64;      // 18 chunks
  const int c   = blockIdx.y;           // [0,10)
  const int t   = threadIdx.x;
  // coalesced read: 64 rows x 128 f32
  for (int idx = t; idx < 64 * 128; idx += 256) {
    const int rsl = idx >> 7, j = idx & 127;
    const int rs = rs0 + rsl;
    const int pos = rs >> 5, cc = rs & 31;
    const int r_true = cc * 36 + pos;
    tile[rsl][j] = rw[(size_t)(c * 1152 + r_true) * 128 + j];
  }
  __syncthreads();
  // coalesced write: for each o, 64 rs x 8 kk consecutive f16
  for (int idx = t; idx < 16 * 64 * 8; idx += 256) {
    const int o = idx >> 9, rem = idx & 511;
    const int rsl = rem >> 3, kk = rem & 7;
    rwh[((size_t)(c * 16 + o) * 1152 + rs0 + rsl) * 8 + kk] =
        (f16)tile[rsl][kk * 16 + o];
  }
}

// ---------------- FUSED priors + dynamic routing, one block per (b,c) ------
// 512 threads, P[3][16]; w-reads coalesced via transposed rwh; dot8 per P.
__device__ __forceinline__ float wave_sum(float v) {
#pragma unroll
  for (int off = 32; off > 0; off >>= 1) v += __shfl_xor(v, off);
  return v;
}
__device__ __forceinline__ float wave_max(float v) {
#pragma unroll
  for (int off = 32; off > 0; off >>= 1) v = fmaxf(v, __shfl_xor(v, off));
  return v;
}

__global__ __launch_bounds__(512, 2) void routing_kernel(
    const f16* __restrict__ u16, const f16* __restrict__ rwh,
    float* __restrict__ caps)
{
  const int c = blockIdx.x % 10;
  const int b = blockIdx.x / 10;
  const int t = threadIdx.x;            // 0..511
  const int wid = t >> 6;               // 0..7
  const int lane = t & 63;
  __shared__ float xred[8 * 17];

  float P[3][16];
  float lg[3];
  const int nk = (t < 128) ? 3 : 2;
#pragma unroll
  for (int k = 0; k < 3; ++k)
#pragma unroll
    for (int o = 0; o < 16; ++o) P[k][o] = 0.f;

  // ---- fused priors: P[k][o] = dot8(u[b,rs,:], rwh[c,o,rs,:]) ----
  const f16* ub = u16 + (size_t)b * 9216;           // b*1152*8
  const f16* wb = rwh + (size_t)c * 147456;         // c*16*1152*8

#define PRIORS_ROW(K)                                                         \
  {                                                                           \
    const int rs = t + ((K) << 9);                                            \
    const f16x8 uv = *(const f16x8*)&ub[(size_t)rs * 8];                      \
    _Pragma("unroll") for (int o = 0; o < 16; ++o) {                          \
      const f16x8 wv = *(const f16x8*)&wb[((size_t)o * 1152 + rs) * 8];       \
      P[K][o] = dot8(uv, wv);                                                 \
      if (o == 7) __builtin_amdgcn_sched_barrier(0);                          \
    }                                                                         \
  }

  PRIORS_ROW(0);
  __builtin_amdgcn_sched_barrier(0);
  PRIORS_ROW(1);
  __builtin_amdgcn_sched_barrier(0);
  if (t < 128) PRIORS_ROW(2);
  __builtin_amdgcn_sched_barrier(0);
#undef PRIORS_ROW

  float v[16];
  {
    float sq = 0.f;
#pragma unroll
    for (int o = 0; o < 16; ++o) {
      float p = P[0][o] + P[1][o] + P[2][o];   // P[2]=0 for inactive threads
      p = wave_sum(p);
      if (lane == 0) xred[wid * 17 + o] = p;
      v[o] = 0.f;
    }
    __syncthreads();
#pragma unroll
    for (int o = 0; o < 16; ++o) {
      float s = 0.f;
#pragma unroll
      for (int w = 0; w < 8; ++w) s += xred[w * 17 + o];
      s *= (1.f / 1152.f);
      v[o] = s;
      sq = fmaf(s, s, sq);
    }
    const float scale = sq / ((1.f + sq) * sqrtf(sq));
#pragma unroll
    for (int o = 0; o < 16; ++o) v[o] *= scale;
    __syncthreads();
  }
#pragma unroll
  for (int k = 0; k < 3; ++k) {
    float a = 0.f;
#pragma unroll
    for (int o = 0; o < 16; ++o) a = fmaf(P[k][o], v[o], a);
    lg[k] = a;                                // lg[2]=0 for inactive threads
  }

  for (int it = 1; it < 3; ++it) {
    float m = -1e30f;
#pragma unroll
    for (int k = 0; k < 3; ++k) if (k < nk) m = fmaxf(m, lg[k]);
    m = wave_max(m);
    if (lane == 0) xred[wid * 17 + 16] = m;
    __syncthreads();
    float mx = xred[16];
#pragma unroll
    for (int w = 1; w < 8; ++w) mx = fmaxf(mx, xred[w * 17 + 16]);
    __syncthreads();
    float e[3];
#pragma unroll
    for (int k = 0; k < 3; ++k) e[k] = (k < nk) ? expf(lg[k] - mx) : 0.f;
    float pS = e[0] + e[1] + e[2];
    pS = wave_sum(pS);
    if (lane == 0) xred[wid * 17 + 16] = pS;
#pragma unroll
    for (int o = 0; o < 16; ++o) {
      float p = 0.f;
#pragma unroll
      for (int k = 0; k < 3; ++k) p = fmaf(e[k], P[k][o], p);
      p = wave_sum(p);
      if (lane == 0) xred[wid * 17 + o] = p;
    }
    __syncthreads();
    float S = 0.f;
#pragma unroll
    for (int w = 0; w < 8; ++w) S += xred[w * 17 + 16];
    const float inv = 1.f / S;
    float sq = 0.f;
#pragma unroll
    for (int o = 0; o < 16; ++o) {
      float s = 0.f;
#pragma unroll
      for (int w = 0; w < 8; ++w) s += xred[w * 17 + o];
      s *= inv;
      v[o] = s;
      sq = fmaf(s, s, sq);
    }
    const float scale = sq / ((1.f + sq) * sqrtf(sq));
#pragma unroll
    for (int o = 0; o < 16; ++o) v[o] *= scale;
    __syncthreads();
    if (it < 2) {
#pragma unroll
      for (int k = 0; k < 3; ++k) {
        float a = 0.f;
#pragma unroll
        for (int o = 0; o < 16; ++o) a = fmaf(P[k][o], v[o], a);
        lg[k] += a;
      }
    }
  }
  if (t == 0) {
    float* cp = &caps[(b * 10 + c) * 16];
#pragma unroll
    for (int o = 0; o < 16; ++o) cp[o] = v[o];
  }
}

// --------- classes softmax + argmax one-hot mask ---------------------------
__global__ void classes_kernel(const float* __restrict__ caps,
                               float* __restrict__ out_classes,
                               float* __restrict__ d0)
{
  const int b = blockIdx.x * 256 + threadIdx.x;
  if (b >= 512) return;
  float nrm[10];
#pragma unroll
  for (int cc = 0; cc < 10; ++cc) {
    float sq = 0.f;
#pragma unroll
    for (int o = 0; o < 16; ++o) {
      const float vv = caps[(b * 10 + cc) * 16 + o];
      sq = fmaf(vv, vv, sq);
    }
    nrm[cc] = sqrtf(sq);
  }
  float mx = nrm[0]; int cs = 0;
#pragma unroll
  for (int cc = 1; cc < 10; ++cc)
    if (nrm[cc] > mx) { mx = nrm[cc]; cs = cc; }
  float e[10], ssum = 0.f;
#pragma unroll
  for (int cc = 0; cc < 10; ++cc) { e[cc] = expf(nrm[cc] - mx); ssum += e[cc]; }
  const float inv = 1.f / ssum;
#pragma unroll
  for (int cc = 0; cc < 10; ++cc) out_classes[b * 10 + cc] = e[cc] * inv;
#pragma unroll
  for (int cc = 0; cc < 10; ++cc)
#pragma unroll
    for (int o = 0; o < 16; ++o)
      d0[b * 160 + cc * 16 + o] = (cc == cs) ? caps[(b * 10 + cc) * 16 + o] : 0.f;
}

// --------- decoder GEMM: C[M,N] = act(A[M,K] @ W[N,K]^T + bias) ------------
__global__ __launch_bounds__(256, 2) void fc_kernel(
    const float* __restrict__ A, const float* __restrict__ W,
    const float* __restrict__ bias, float* __restrict__ C,
    int N, int K, int act)
{
  __shared__ float As[64][17];
  __shared__ float Ws[64][17];
  const int t = threadIdx.x;
  const int tm = t >> 4, tn = t & 15;
  const int m0 = blockIdx.y << 6, n0 = blockIdx.x << 6;
  const int lr = t >> 2, lq = (t & 3) << 2;
  float acc[4][4] = {};
  for (int k0 = 0; k0 < K; k0 += 16) {
    const float4 av = *(const float4*)&A[(m0 + lr) * K + k0 + lq];
    float4 wv = make_float4(0.f, 0.f, 0.f, 0.f);
    const int wn = n0 + lr;
    if (wn < N) wv = *(const float4*)&W[wn * K + k0 + lq];
    __syncthreads();
    As[lr][lq+0] = av.x; As[lr][lq+1] = av.y; As[lr][lq+2] = av.z; As[lr][lq+3] = av.w;
    Ws[lr][lq+0] = wv.x; Ws[lr][lq+1] = wv.y; Ws[lr][lq+2] = wv.z; Ws[lr][lq+3] = wv.w;
    __syncthreads();
#pragma unroll
    for (int kk = 0; kk < 16; ++kk) {
      float a[4], w[4];
#pragma unroll
      for (int i = 0; i < 4; ++i) a[i] = As[tm * 4 + i][kk];
#pragma unroll
      for (int j = 0; j < 4; ++j) w[j] = Ws[tn * 4 + j][kk];
#pragma unroll
      for (int i = 0; i < 4; ++i)
#pragma unroll
        for (int j = 0; j < 4; ++j) acc[i][j] = fmaf(a[i], w[j], acc[i][j]);
    }
  }
#pragma unroll
  for (int i = 0; i < 4; ++i) {
    const int m = m0 + tm * 4 + i;
#pragma unroll
    for (int j = 0; j < 4; ++j) {
      const int n = n0 + tn * 4 + j;
      if (n < N) {
        float vv = acc[i][j] + bias[n];
        vv = act ? (1.f / (1.f + expf(-vv))) : fmaxf(vv, 0.f);
        C[m * N + n] = vv;
      }
    }
  }
}

// ============================================================================
extern "C" void kernel_launch(void* const* d_in, const int* in_sizes, int n_in,
                              void* d_out, int out_size, void* d_ws, size_t ws_size,
                              hipStream_t stream)
{
  const float* x       = (const float*)d_in[0];
  const float* conv1_w = (const float*)d_in[1];
  const float* conv1_b = (const float*)d_in[2];
  const float* prim_w  = (const float*)d_in[3];
  const float* prim_b  = (const float*)d_in[4];
  const float* route_w = (const float*)d_in[5];
  const float* dec_w1  = (const float*)d_in[6];
  const float* dec_b1  = (const float*)d_in[7];
  const float* dec_w2  = (const float*)d_in[8];
  const float* dec_b2  = (const float*)d_in[9];
  const float* dec_w3  = (const float*)d_in[10];
  const float* dec_b3  = (const float*)d_in[11];
  float* out = (float*)d_out;

  char* ws = (char*)d_ws;
  f16*   ht   = (f16*)(ws);                        // 104,857,600 B
  f16*   wtp  = (f16*)(ws + 104857600);            //  10,616,832 B
  f16*   part = (f16*)(ws + 115474432);            //  75,497,472 B (8 f16 slices)
  f16*   A16  = (f16*)(ws + 115474432);            //  39,321,600 B (overlays
                                                   //  part; dead before prim)
  f16*   wt1  = (f16*)(ws + 190971904);            //      49,152 B
  f16*   u16  = (f16*)(ws + 191021056);            //   9,437,184 B
  f16*   rwh  = (f16*)(ws);                        //   2,949,120 B (overlays
                                                   //  ht, dead after prim)
  float* caps = (float*)(ws + 200458240);          // 327,680 B
  float* d0   = (float*)(ws + 200785920);          // 327,680 B
  float* d1   = (float*)(ws + 201113600);          // 1,048,576 B
  float* d2   = (float*)(ws + 202162176);          // 2,097,152 B

  hipLaunchKernelGGL(im2col_kernel, dim3(9600), dim3(256), 0, stream, x, A16);
  hipLaunchKernelGGL(c1trans_kernel, dim3(96), dim3(256), 0, stream,
                     conv1_w, wt1);
  hipLaunchKernelGGL(conv1_mfma_kernel, dim3(3200), dim3(256), 0, stream,
                     A16, wt1, conv1_b, ht);
  hipLaunchKernelGGL(wtrans_kernel, dim3(256, 4), dim3(256), 0, stream,
                     prim_w, wtp);
  hipLaunchKernelGGL(prim_mfma_kernel, dim3(2304), dim3(256), 0, stream,
                     ht, wtp, part);
  hipLaunchKernelGGL(rwprep_kernel, dim3(18, 10), dim3(256), 0, stream,
                     route_w, rwh);
  hipLaunchKernelGGL(squash_kernel, dim3(2304), dim3(256), 0, stream,
                     part, prim_b, u16);
  hipLaunchKernelGGL(routing_kernel, dim3(5120), dim3(512), 0, stream,
                     u16, rwh, caps);
  hipLaunchKernelGGL(classes_kernel, dim3(2), dim3(256), 0, stream,
                     caps, out, d0);
  hipLaunchKernelGGL(fc_kernel, dim3(8, 8), dim3(256), 0, stream,
                     d0, dec_w1, dec_b1, d1, 512, 160, 0);
  hipLaunchKernelGGL(fc_kernel, dim3(16, 8), dim3(256), 0, stream,
                     d1, dec_w2, dec_b2, d2, 1024, 512, 0);
  hipLaunchKernelGGL(fc_kernel, dim3(13, 8), dim3(256), 0, stream,
                     d2, dec_w3, dec_b3, out + 5120, 784, 1024, 1);
}

// Round 7
// 821.577 us; speedup vs baseline: 1.9123x; 1.1802x over previous
//
#include <hip/hip_runtime.h>
#include <math.h>

// ============================================================================
// CapsuleNet forward, round 20.
// R19 post-mortem: routing 385us, stall-dominated (VALU 25%, HBM 1.4%, occ
//   23.5% ~ 1 block/CU). Root cause: P[3][16] f32 in regs -> 116 VGPR ->
//   (a) low occupancy, (b) the 17-way independent shfl reduce chains can't
//   interleave (no free temps) -> serialized 6-deep bpermute latency chains.
// Fix: P lives in LDS as f16 (36.9KB, XOR-swizzled 16B chunks, verified
//   bijective + conflict-free for rs=lane patterns). 384 thr (nk=3 uniform,
//   1152=384*3). Per row: compute P_k[16] in regs, ds_write_b128 x2, free.
//   Iterations re-read own rows (24 ds_read_b128/thread). launch_bounds
//   (384,5) caps VGPR 102 -> 3-4 blocks/CU (LDS caps 4). Expect occ 23->50+%,
//   routing 385 -> 150-200us.
// prim: R15 kept. conv1/im2col/wtrans/squash/rwprep/classes/fc unchanged.
// ============================================================================

typedef _Float16 f16;
typedef _Float16 f16x8 __attribute__((ext_vector_type(8)));
typedef _Float16 f16x4 __attribute__((ext_vector_type(4)));
typedef _Float16 f16x2 __attribute__((ext_vector_type(2)));
typedef float f32x4 __attribute__((ext_vector_type(4)));

__device__ __forceinline__ void gl_lds16(const void* g, void* l) {
  __builtin_amdgcn_global_load_lds(
      (const __attribute__((address_space(1))) void*)g,
      (__attribute__((address_space(3))) void*)l, 16, 0, 0);
}

__device__ __forceinline__ float dot8(f16x8 a, f16x8 b) {
#if __has_builtin(__builtin_amdgcn_fdot2)
  float s = 0.f;
#pragma unroll
  for (int j = 0; j < 4; ++j) {
    f16x2 av, bv;
    av[0] = a[2 * j]; av[1] = a[2 * j + 1];
    bv[0] = b[2 * j]; bv[1] = b[2 * j + 1];
    s = __builtin_amdgcn_fdot2(av, bv, s, false);
  }
  return s;
#else
  float s = 0.f;
#pragma unroll
  for (int i = 0; i < 8; ++i) s = fmaf((float)a[i], (float)b[i], s);
  return s;
#endif
}

// swizzled byte offset of the 16B half-chunk (rs, h) in the P LDS tile.
// chunk = rs*2+h; low 3 bits XORed with rs&7 -> bijective per 128B group,
// conflict-free for lane-consecutive rs.
__device__ __forceinline__ int pswz(int rs, int h) {
  return (((rs * 2 + h) ^ (rs & 7)) * 16);
}

// --------- im2col: x[512,1,28,28] fp32 -> A16[m=204800][96] f16 ------------
__global__ void im2col_kernel(const float* __restrict__ x, f16* __restrict__ A)
{
  const int c = blockIdx.x * 256 + threadIdx.x;    // 2,457,600 exact
  const int m = c / 12, kc = c - m * 12;
  const int b = m / 400, rem = m - b * 400;
  const int oy = rem / 20, ox = rem - oy * 20;
  const float* xb = x + b * 784;
  f16x8 v;
#pragma unroll
  for (int j = 0; j < 8; ++j) {
    const int k = kc * 8 + j;
    float val = 0.f;
    if (k < 81) {
      const int ky = k / 9, kx = k - ky * 9;
      val = xb[(oy + ky) * 28 + ox + kx];
    }
    v[j] = (f16)val;
  }
  *(f16x8*)&A[(size_t)m * 96 + kc * 8] = v;
}

// --------- c1trans: conv1_w fp32 [256][81] -> wt1 f16 [256][96] (pad 0) ----
__global__ void c1trans_kernel(const float* __restrict__ w, f16* __restrict__ wt1)
{
  const int idx = blockIdx.x * 256 + threadIdx.x;  // 24576 exact
  const int oc = idx / 96, k = idx - oc * 96;
  wt1[idx] = (k < 81) ? (f16)w[oc * 81 + k] : (f16)0.f;
}

// --------- conv1 GEMM: ht[m][oc] = relu(A16 @ wt1^T + bias) ----------------
__global__ __launch_bounds__(256) void conv1_mfma_kernel(
    const f16* __restrict__ A, const f16* __restrict__ wt1,
    const float* __restrict__ bias, f16* __restrict__ ht)
{
  __shared__ f16 sm[8192];            // As[0..4096) | Bs[4096..8192)
  const int t = threadIdx.x;
  const int wv = t >> 6, lane = t & 63;
  const int id = blockIdx.x;
  const int mb = id >> 1, nb = id & 1;
  const int m0 = mb * 128, n0 = nb * 128;

  const int chunk = (lane & 3) ^ ((lane >> 3) & 3);
  long aoff[2], boff[2];
#pragma unroll
  for (int i = 0; i < 2; ++i) {
    const int r = wv * 32 + i * 16 + (lane >> 2);
    aoff[i] = (long)(m0 + r) * 192 + chunk * 16;
    boff[i] = (long)(n0 + r) * 192 + chunk * 16;
  }
  const char* ac = (const char*)A;
  const char* bc = (const char*)wt1;

  const int lrow = lane & 15, quad = lane >> 4;
  const int qx = quad ^ ((lrow >> 1) & 3);
  const int wm = wv & 1, wn = wv >> 1;
  f32x4 acc[4][4] = {};

  for (int s = 0; s < 3; ++s) {
    const long kstep = (long)s * 64;
    __syncthreads();
    {
      char* dA = (char*)sm + wv * 2048;
      char* dB = (char*)sm + 8192 + wv * 2048;
      gl_lds16(ac + aoff[0] + kstep, dA);
      gl_lds16(ac + aoff[1] + kstep, dA + 1024);
      gl_lds16(bc + boff[0] + kstep, dB);
      gl_lds16(bc + boff[1] + kstep, dB + 1024);
    }
    __syncthreads();
    const f16* As = sm;
    const f16* Bs = sm + 4096;
    f16x8 af[4], bf[4];
#pragma unroll
    for (int mt = 0; mt < 4; ++mt)
      af[mt] = *(const f16x8*)&As[(wm * 64 + mt * 16 + lrow) * 32 + qx * 8];
#pragma unroll
    for (int nt = 0; nt < 4; ++nt)
      bf[nt] = *(const f16x8*)&Bs[(wn * 64 + nt * 16 + lrow) * 32 + qx * 8];
#pragma unroll
    for (int mt = 0; mt < 4; ++mt)
#pragma unroll
      for (int nt = 0; nt < 4; ++nt)
        acc[mt][nt] = __builtin_amdgcn_mfma_f32_16x16x32_f16(
            af[mt], bf[nt], acc[mt][nt], 0, 0, 0);
  }

  // epilogue: ht[m*256 + oc] = relu(acc + bias[oc]) as f16 (NHWC, y/x in m)
#pragma unroll
  for (int nt = 0; nt < 4; ++nt) {
    const int n = n0 + wn * 64 + nt * 16 + lrow;          // col=lane&15
    const float bv = bias[n];
#pragma unroll
    for (int mt = 0; mt < 4; ++mt) {
      const int mbase = m0 + wm * 64 + mt * 16 + quad * 4; // row=quad*4+reg
#pragma unroll
      for (int rg = 0; rg < 4; ++rg)
        ht[(size_t)(mbase + rg) * 256 + n] =
            (f16)fmaxf(acc[mt][nt][rg] + bv, 0.f);
    }
  }
}

// --------- wtrans: prim_w fp32 [oc][ic][kykx] -> wt fp16 [oc][kykx][ic] ----
__global__ __launch_bounds__(256) void wtrans_kernel(
    const float* __restrict__ w, f16* __restrict__ wt)
{
  __shared__ float tile[64 * 83];
  const int oc = blockIdx.x;
  const int icq = blockIdx.y;
  const int t = threadIdx.x;
  const float* src = w + (size_t)oc * 20736 + (size_t)icq * 64 * 81;
  for (int idx = t; idx < 5184; idx += 256) {
    const int ici = idx / 81, kk = idx - ici * 81;
    tile[ici * 83 + kk] = src[idx];
  }
  __syncthreads();
  f16* dst = wt + (size_t)oc * 20736 + icq * 64;
  for (int idx = t; idx < 5184; idx += 256) {
    const int kk = idx >> 6, ici = idx & 63;
    dst[kk * 256 + ici] = (f16)tile[ici * 83 + kk];
  }
}

// ---------------- primary caps conv: MFMA implicit GEMM, split-K 8 ---------
// grid 2304 = 144 mb x 2 nb x 8 ks = exactly 3 rounds at 3 blocks/CU.
__global__ __launch_bounds__(256) void prim_mfma_kernel(
    const f16* __restrict__ ht, const f16* __restrict__ wt,
    f16* __restrict__ part)
{
  __shared__ f16 sm[24576];           // 48 KB: 3 buffers of [A 8KB | B 8KB]
  const int t = threadIdx.x;
  const int wv = t >> 6, lane = t & 63;
  const int id = blockIdx.x;
  const int ks = (id >> 3) & 7;                   // 8 K-slices
  const int nb = (id >> 6) & 1;
  const int mb = (id & 7) + 8 * (id >> 7);        // same-mb ids === mod 8
  const int m0 = mb * 128, n0 = nb * 128;

  const int chunk = (lane & 3) ^ ((lane >> 3) & 3);
  long aoff[2], boff[2];
#pragma unroll
  for (int i = 0; i < 2; ++i) {
    const int r = wv * 32 + i * 16 + (lane >> 2);
    const int m = m0 + r;
    const int b = m / 36, pos = m - b * 36;
    const int oy = pos / 6, ox = pos - oy * 6;
    aoff[i] = (long)(((b * 20 + 2 * oy) * 20 + 2 * ox) * 256) * 2 + chunk * 16;
    boff[i] = (long)(n0 + r) * 41472 + chunk * 16;   // oc*81*256*2
  }
  const char* htc = (const char*)ht;
  const char* wtc = (const char*)wt;

  const int lrow = lane & 15, quad = lane >> 4;
  const int qx = quad ^ ((lrow >> 1) & 3);
  const int wm = wv & 1, wn = wv >> 1;
  f32x4 acc[4][4] = {};

  const int s0 = ks * 81;             // 81 stages per slice

#define STAGE(S, BUFB)                                                        \
  {                                                                           \
    const int kykx = (S) >> 3, icb = (S) & 7;                                 \
    const int ky = kykx / 9, kx = kykx - ky * 9;                              \
    const long astep = (long)((((ky * 20 + kx) * 256) + icb * 32) * 2);       \
    const long bstep = (long)(((kykx * 256) + icb * 32) * 2);                 \
    char* dA = (char*)sm + (BUFB) + wv * 2048;                                \
    char* dB = (char*)sm + (BUFB) + 8192 + wv * 2048;                         \
    gl_lds16(htc + aoff[0] + astep, dA);                                      \
    gl_lds16(htc + aoff[1] + astep, dA + 1024);                               \
    gl_lds16(wtc + boff[0] + bstep, dB);                                      \
    gl_lds16(wtc + boff[1] + bstep, dB + 1024);                               \
  }

#define CONSUME(BUFI)                                                         \
  {                                                                           \
    const f16* As = sm + (BUFI);                                              \
    const f16* Bs = sm + (BUFI) + 4096;                                       \
    f16x8 af[4], bf[4];                                                       \
    _Pragma("unroll") for (int mt = 0; mt < 4; ++mt)                          \
        af[mt] = *(const f16x8*)&As[(wm * 64 + mt * 16 + lrow) * 32 + qx * 8];\
    _Pragma("unroll") for (int nt = 0; nt < 4; ++nt)                          \
        bf[nt] = *(const f16x8*)&Bs[(wn * 64 + nt * 16 + lrow) * 32 + qx * 8];\
    _Pragma("unroll") for (int mt = 0; mt < 4; ++mt)                          \
        _Pragma("unroll") for (int nt = 0; nt < 4; ++nt)                      \
            acc[mt][nt] = __builtin_amdgcn_mfma_f32_16x16x32_f16(             \
                af[mt], bf[nt], acc[mt][nt], 0, 0, 0);                        \
  }

  // depth-2 pipeline, 3 buffers (byte offsets 0 / 16384 / 32768)
  STAGE(s0, 0);
  STAGE(s0 + 1, 16384);
  int bS = 32768;                     // stage target:   (K+2)%3
  int bC = 0;                         // consume buffer:  K   %3
  for (int K = 0; K < 79; ++K) {
    asm volatile("s_waitcnt vmcnt(4)" ::: "memory");  // own stage-K writes done
    __builtin_amdgcn_s_barrier();                     // publish to all waves
    asm volatile("" ::: "memory");
    STAGE(s0 + K + 2, bS);
    __builtin_amdgcn_s_setprio(1);
    CONSUME(bC >> 1);
    __builtin_amdgcn_s_setprio(0);
    bS += 16384; if (bS == 49152) bS = 0;
    bC += 16384; if (bC == 49152) bC = 0;
  }
  // K = 79: stages 79,80 in flight; wait 79 (4 newest = stage 80 may fly)
  asm volatile("s_waitcnt vmcnt(4)" ::: "memory");
  __builtin_amdgcn_s_barrier();
  asm volatile("" ::: "memory");
  __builtin_amdgcn_s_setprio(1);
  CONSUME(bC >> 1);
  __builtin_amdgcn_s_setprio(0);
  bC += 16384; if (bC == 49152) bC = 0;
  // K = 80: wait everything
  asm volatile("s_waitcnt vmcnt(0)" ::: "memory");
  __builtin_amdgcn_s_barrier();
  asm volatile("" ::: "memory");
  CONSUME(bC >> 1);
#undef STAGE
#undef CONSUME

  // epilogue: f16 partials, 8 slices of [18432][256], permuted np layout
  f16* pp = part + (size_t)ks * 4718592;
#pragma unroll
  for (int mt = 0; mt < 4; ++mt) {
    const int mbase = m0 + wm * 64 + mt * 16 + quad * 4;
#pragma unroll
    for (int nt = 0; nt < 4; ++nt) {
      const int n = n0 + wn * 64 + nt * 16 + lrow;
      const int np = (n & 31) * 8 + (n >> 5);
#pragma unroll
      for (int rg = 0; rg < 4; ++rg)
        pp[(size_t)(mbase + rg) * 256 + np] = (f16)acc[mt][nt][rg];
    }
  }
}

// --------- split-K(8) reduce + bias + squash -> u16[512][rs=pos*32+cc][8] --
__global__ void squash_kernel(const f16* __restrict__ part,
                              const float* __restrict__ bias,
                              f16* __restrict__ u16)
{
  const int tid = blockIdx.x * 256 + threadIdx.x;   // (b*36+pos)*32 + cc
  if (tid >= 512 * 36 * 32) return;
  const int cc = tid & 31;
  const int row = tid >> 5;                         // b*36 + pos
  const int b = row / 36;
  const int pos = row - b * 36;
  const f16* p = part + (size_t)row * 256 + cc * 8;
  float v[8] = {};
#pragma unroll
  for (int ksl = 0; ksl < 8; ++ksl) {
    const f16x8 a = *(const f16x8*)(p + (size_t)ksl * 4718592);
#pragma unroll
    for (int i = 0; i < 8; ++i) v[i] += (float)a[i];
  }
  float sq = 0.f;
#pragma unroll
  for (int i = 0; i < 8; ++i) {
    v[i] += bias[i * 32 + cc];
    sq = fmaf(v[i], v[i], sq);
  }
  const float scale = sq / ((1.f + sq) * sqrtf(sq));
  f16x8 st;
#pragma unroll
  for (int i = 0; i < 8; ++i) st[i] = (f16)(v[i] * scale);
  *(f16x8*)&u16[(size_t)(b * 1152 + pos * 32 + cc) * 8] = st;   // contiguous
}

// --------- rwprep: route_w f32 [c][r_true][8][16] -> rwh f16 [c][o][rs][kk] -
// transposed so routing's per-o wave-loads are lane-contiguous (16B/lane).
__global__ __launch_bounds__(256) void rwprep_kernel(
    const float* __restrict__ rw, f16* __restrict__ rwh)
{
  __shared__ float tile[64][129];
  const int rs0 = blockIdx.x * 64;      // 18 chunks
  const int c   = blockIdx.y;           // [0,10)
  const int t   = threadIdx.x;
  // coalesced read: 64 rows x 128 f32
  for (int idx = t; idx < 64 * 128; idx += 256) {
    const int rsl = idx >> 7, j = idx & 127;
    const int rs = rs0 + rsl;
    const int pos = rs >> 5, cc = rs & 31;
    const int r_true = cc * 36 + pos;
    tile[rsl][j] = rw[(size_t)(c * 1152 + r_true) * 128 + j];
  }
  __syncthreads();
  // coalesced write: for each o, 64 rs x 8 kk consecutive f16
  for (int idx = t; idx < 16 * 64 * 8; idx += 256) {
    const int o = idx >> 9, rem = idx & 511;
    const int rsl = rem >> 3, kk = rem & 7;
    rwh[((size_t)(c * 16 + o) * 1152 + rs0 + rsl) * 8 + kk] =
        (f16)tile[rsl][kk * 16 + o];
  }
}

// ---------------- FUSED priors + dynamic routing, one block per (b,c) ------
// 384 threads, nk=3 uniform. P stored in LDS as f16 (XOR-swizzled) to free
// registers: occupancy up + shfl chains interleave.
__device__ __forceinline__ float wave_sum(float v) {
#pragma unroll
  for (int off = 32; off > 0; off >>= 1) v += __shfl_xor(v, off);
  return v;
}
__device__ __forceinline__ float wave_max(float v) {
#pragma unroll
  for (int off = 32; off > 0; off >>= 1) v = fmaxf(v, __shfl_xor(v, off));
  return v;
}

__global__ __launch_bounds__(384, 5) void routing_kernel(
    const f16* __restrict__ u16, const f16* __restrict__ rwh,
    float* __restrict__ caps)
{
  __shared__ __align__(16) f16 Pl[1152 * 16];   // 36,864 B, swizzled
  __shared__ float xred[6 * 17];
  const int c = blockIdx.x % 10;
  const int b = blockIdx.x / 10;
  const int t = threadIdx.x;            // 0..383
  const int wid = t >> 6;               // 0..5
  const int lane = t & 63;

  const f16* ub = u16 + (size_t)b * 9216;           // b*1152*8
  const f16* wb = rwh + (size_t)c * 147456;         // c*16*1152*8
  char* Pb = (char*)Pl;

  float psum[16];
#pragma unroll
  for (int o = 0; o < 16; ++o) psum[o] = 0.f;

  // ---- priors: per row, compute P_k[16] in regs, store f16 row to LDS ----
#pragma unroll
  for (int k = 0; k < 3; ++k) {
    const int rs = t + k * 384;
    const f16x8 uv = *(const f16x8*)&ub[(size_t)rs * 8];
    float Pk[16];
#pragma unroll
    for (int o = 0; o < 16; ++o) {
      const f16x8 wv = *(const f16x8*)&wb[((size_t)o * 1152 + rs) * 8];
      Pk[o] = dot8(uv, wv);
      if (o == 7) __builtin_amdgcn_sched_barrier(0);
    }
    f16x8 h0, h1;
#pragma unroll
    for (int j = 0; j < 8; ++j) { h0[j] = (f16)Pk[j]; h1[j] = (f16)Pk[j + 8]; }
    *(f16x8*)(Pb + pswz(rs, 0)) = h0;
    *(f16x8*)(Pb + pswz(rs, 1)) = h1;
#pragma unroll
    for (int o = 0; o < 16; ++o) psum[o] += Pk[o];
    __builtin_amdgcn_sched_barrier(0);
  }

  // ---- it0: v = squash(mean of P) ----
  float v[16];
  {
    float sq = 0.f;
#pragma unroll
    for (int o = 0; o < 16; ++o) {
      float p = wave_sum(psum[o]);
      if (lane == 0) xred[wid * 17 + o] = p;
    }
    __syncthreads();   // also publishes Pl writes
#pragma unroll
    for (int o = 0; o < 16; ++o) {
      float s = 0.f;
#pragma unroll
      for (int w = 0; w < 6; ++w) s += xred[w * 17 + o];
      s *= (1.f / 1152.f);
      v[o] = s;
      sq = fmaf(s, s, sq);
    }
    const float scale = sq / ((1.f + sq) * sqrtf(sq));
#pragma unroll
    for (int o = 0; o < 16; ++o) v[o] *= scale;
    __syncthreads();
  }

  // ---- lg init: lg[k] = P[rs_k][:] . v ----
  float lg[3];
#pragma unroll
  for (int k = 0; k < 3; ++k) {
    const int rs = t + k * 384;
    const f16x8 a0 = *(const f16x8*)(Pb + pswz(rs, 0));
    const f16x8 a1 = *(const f16x8*)(Pb + pswz(rs, 1));
    float a = 0.f;
#pragma unroll
    for (int j = 0; j < 8; ++j) {
      a = fmaf((float)a0[j], v[j], a);
      a = fmaf((float)a1[j], v[j + 8], a);
    }
    lg[k] = a;
  }

  for (int it = 1; it < 3; ++it) {
    float m = fmaxf(fmaxf(lg[0], lg[1]), lg[2]);
    m = wave_max(m);
    if (lane == 0) xred[wid * 17 + 16] = m;
    __syncthreads();
    float mx = xred[16];
#pragma unroll
    for (int w = 1; w < 6; ++w) mx = fmaxf(mx, xred[w * 17 + 16]);
    __syncthreads();
    float e[3];
#pragma unroll
    for (int k = 0; k < 3; ++k) e[k] = expf(lg[k] - mx);
    float pS = e[0] + e[1] + e[2];
    pS = wave_sum(pS);
    if (lane == 0) xred[wid * 17 + 16] = pS;
    // e-weighted P sums (read rows from LDS)
    float acc[16];
#pragma unroll
    for (int o = 0; o < 16; ++o) acc[o] = 0.f;
#pragma unroll
    for (int k = 0; k < 3; ++k) {
      const int rs = t + k * 384;
      const f16x8 a0 = *(const f16x8*)(Pb + pswz(rs, 0));
      const f16x8 a1 = *(const f16x8*)(Pb + pswz(rs, 1));
#pragma unroll
      for (int j = 0; j < 8; ++j) {
        acc[j]     = fmaf(e[k], (float)a0[j], acc[j]);
        acc[j + 8] = fmaf(e[k], (float)a1[j], acc[j + 8]);
      }
    }
#pragma unroll
    for (int o = 0; o < 16; ++o) {
      float p = wave_sum(acc[o]);
      if (lane == 0) xred[wid * 17 + o] = p;
    }
    __syncthreads();
    float S = 0.f;
#pragma unroll
    for (int w = 0; w < 6; ++w) S += xred[w * 17 + 16];
    const float inv = 1.f / S;
    float sq = 0.f;
#pragma unroll
    for (int o = 0; o < 16; ++o) {
      float s = 0.f;
#pragma unroll
      for (int w = 0; w < 6; ++w) s += xred[w * 17 + o];
      s *= inv;
      v[o] = s;
      sq = fmaf(s, s, sq);
    }
    const float scale = sq / ((1.f + sq) * sqrtf(sq));
#pragma unroll
    for (int o = 0; o < 16; ++o) v[o] *= scale;
    __syncthreads();
    if (it < 2) {
#pragma unroll
      for (int k = 0; k < 3; ++k) {
        const int rs = t + k * 384;
        const f16x8 a0 = *(const f16x8*)(Pb + pswz(rs, 0));
        const f16x8 a1 = *(const f16x8*)(Pb + pswz(rs, 1));
        float a = 0.f;
#pragma unroll
        for (int j = 0; j < 8; ++j) {
          a = fmaf((float)a0[j], v[j], a);
          a = fmaf((float)a1[j], v[j + 8], a);
        }
        lg[k] += a;
      }
    }
  }
  if (t == 0) {
    float* cp = &caps[(b * 10 + c) * 16];
#pragma unroll
    for (int o = 0; o < 16; ++o) cp[o] = v[o];
  }
}

// --------- classes softmax + argmax one-hot mask ---------------------------
__global__ void classes_kernel(const float* __restrict__ caps,
                               float* __restrict__ out_classes,
                               float* __restrict__ d0)
{
  const int b = blockIdx.x * 256 + threadIdx.x;
  if (b >= 512) return;
  float nrm[10];
#pragma unroll
  for (int cc = 0; cc < 10; ++cc) {
    float sq = 0.f;
#pragma unroll
    for (int o = 0; o < 16; ++o) {
      const float vv = caps[(b * 10 + cc) * 16 + o];
      sq = fmaf(vv, vv, sq);
    }
    nrm[cc] = sqrtf(sq);
  }
  float mx = nrm[0]; int cs = 0;
#pragma unroll
  for (int cc = 1; cc < 10; ++cc)
    if (nrm[cc] > mx) { mx = nrm[cc]; cs = cc; }
  float e[10], ssum = 0.f;
#pragma unroll
  for (int cc = 0; cc < 10; ++cc) { e[cc] = expf(nrm[cc] - mx); ssum += e[cc]; }
  const float inv = 1.f / ssum;
#pragma unroll
  for (int cc = 0; cc < 10; ++cc) out_classes[b * 10 + cc] = e[cc] * inv;
#pragma unroll
  for (int cc = 0; cc < 10; ++cc)
#pragma unroll
    for (int o = 0; o < 16; ++o)
      d0[b * 160 + cc * 16 + o] = (cc == cs) ? caps[(b * 10 + cc) * 16 + o] : 0.f;
}

// --------- decoder GEMM: C[M,N] = act(A[M,K] @ W[N,K]^T + bias) ------------
__global__ __launch_bounds__(256, 2) void fc_kernel(
    const float* __restrict__ A, const float* __restrict__ W,
    const float* __restrict__ bias, float* __restrict__ C,
    int N, int K, int act)
{
  __shared__ float As[64][17];
  __shared__ float Ws[64][17];
  const int t = threadIdx.x;
  const int tm = t >> 4, tn = t & 15;
  const int m0 = blockIdx.y << 6, n0 = blockIdx.x << 6;
  const int lr = t >> 2, lq = (t & 3) << 2;
  float acc[4][4] = {};
  for (int k0 = 0; k0 < K; k0 += 16) {
    const float4 av = *(const float4*)&A[(m0 + lr) * K + k0 + lq];
    float4 wv = make_float4(0.f, 0.f, 0.f, 0.f);
    const int wn = n0 + lr;
    if (wn < N) wv = *(const float4*)&W[wn * K + k0 + lq];
    __syncthreads();
    As[lr][lq+0] = av.x; As[lr][lq+1] = av.y; As[lr][lq+2] = av.z; As[lr][lq+3] = av.w;
    Ws[lr][lq+0] = wv.x; Ws[lr][lq+1] = wv.y; Ws[lr][lq+2] = wv.z; Ws[lr][lq+3] = wv.w;
    __syncthreads();
#pragma unroll
    for (int kk = 0; kk < 16; ++kk) {
      float a[4], w[4];
#pragma unroll
      for (int i = 0; i < 4; ++i) a[i] = As[tm * 4 + i][kk];
#pragma unroll
      for (int j = 0; j < 4; ++j) w[j] = Ws[tn * 4 + j][kk];
#pragma unroll
      for (int i = 0; i < 4; ++i)
#pragma unroll
        for (int j = 0; j < 4; ++j) acc[i][j] = fmaf(a[i], w[j], acc[i][j]);
    }
  }
#pragma unroll
  for (int i = 0; i < 4; ++i) {
    const int m = m0 + tm * 4 + i;
#pragma unroll
    for (int j = 0; j < 4; ++j) {
      const int n = n0 + tn * 4 + j;
      if (n < N) {
        float vv = acc[i][j] + bias[n];
        vv = act ? (1.f / (1.f + expf(-vv))) : fmaxf(vv, 0.f);
        C[m * N + n] = vv;
      }
    }
  }
}

// ============================================================================
extern "C" void kernel_launch(void* const* d_in, const int* in_sizes, int n_in,
                              void* d_out, int out_size, void* d_ws, size_t ws_size,
                              hipStream_t stream)
{
  const float* x       = (const float*)d_in[0];
  const float* conv1_w = (const float*)d_in[1];
  const float* conv1_b = (const float*)d_in[2];
  const float* prim_w  = (const float*)d_in[3];
  const float* prim_b  = (const float*)d_in[4];
  const float* route_w = (const float*)d_in[5];
  const float* dec_w1  = (const float*)d_in[6];
  const float* dec_b1  = (const float*)d_in[7];
  const float* dec_w2  = (const float*)d_in[8];
  const float* dec_b2  = (const float*)d_in[9];
  const float* dec_w3  = (const float*)d_in[10];
  const float* dec_b3  = (const float*)d_in[11];
  float* out = (float*)d_out;

  char* ws = (char*)d_ws;
  f16*   ht   = (f16*)(ws);                        // 104,857,600 B
  f16*   wtp  = (f16*)(ws + 104857600);            //  10,616,832 B
  f16*   part = (f16*)(ws + 115474432);            //  75,497,472 B (8 f16 slices)
  f16*   A16  = (f16*)(ws + 115474432);            //  39,321,600 B (overlays
                                                   //  part; dead before prim)
  f16*   wt1  = (f16*)(ws + 190971904);            //      49,152 B
  f16*   u16  = (f16*)(ws + 191021056);            //   9,437,184 B
  f16*   rwh  = (f16*)(ws);                        //   2,949,120 B (overlays
                                                   //  ht, dead after prim)
  float* caps = (float*)(ws + 200458240);          // 327,680 B
  float* d0   = (float*)(ws + 200785920);          // 327,680 B
  float* d1   = (float*)(ws + 201113600);          // 1,048,576 B
  float* d2   = (float*)(ws + 202162176);          // 2,097,152 B

  hipLaunchKernelGGL(im2col_kernel, dim3(9600), dim3(256), 0, stream, x, A16);
  hipLaunchKernelGGL(c1trans_kernel, dim3(96), dim3(256), 0, stream,
                     conv1_w, wt1);
  hipLaunchKernelGGL(conv1_mfma_kernel, dim3(3200), dim3(256), 0, stream,
                     A16, wt1, conv1_b, ht);
  hipLaunchKernelGGL(wtrans_kernel, dim3(256, 4), dim3(256), 0, stream,
                     prim_w, wtp);
  hipLaunchKernelGGL(prim_mfma_kernel, dim3(2304), dim3(256), 0, stream,
                     ht, wtp, part);
  hipLaunchKernelGGL(rwprep_kernel, dim3(18, 10), dim3(256), 0, stream,
                     route_w, rwh);
  hipLaunchKernelGGL(squash_kernel, dim3(2304), dim3(256), 0, stream,
                     part, prim_b, u16);
  hipLaunchKernelGGL(routing_kernel, dim3(5120), dim3(384), 0, stream,
                     u16, rwh, caps);
  hipLaunchKernelGGL(classes_kernel, dim3(2), dim3(256), 0, stream,
                     caps, out, d0);
  hipLaunchKernelGGL(fc_kernel, dim3(8, 8), dim3(256), 0, stream,
                     d0, dec_w1, dec_b1, d1, 512, 160, 0);
  hipLaunchKernelGGL(fc_kernel, dim3(16, 8), dim3(256), 0, stream,
                     d1, dec_w2, dec_b2, d2, 1024, 512, 0);
  hipLaunchKernelGGL(fc_kernel, dim3(13, 8), dim3(256), 0, stream,
                     d2, dec_w3, dec_b3, out + 5120, 784, 1024, 1);
}

// Round 8
// 810.420 us; speedup vs baseline: 1.9386x; 1.0138x over previous
//
#include <hip/hip_runtime.h>
#include <math.h>

// ============================================================================
// CapsuleNet forward, round 21.
// R20 post-mortem: routing ~237us by subtraction (385-148). ~95us VALU +
//   ~140us load-latency stall. The stall: R18's anti-spill sched_barrier(0)
//   fences are still in the priors loop -- with P now in LDS they only
//   serialize the 17-load row batches and block cross-row load/compute
//   overlap. Long-lived reg state is tiny now; fences are pure poison.
// Fix: remove ALL sched_barrier fences from the priors phase (compiler now
//   free to hoist a full row's loads and pipeline rows). launch_bounds(384,5)
//   still caps VGPR at 102 so hoisting can't spill far.
// prim: R15 kept. Everything else unchanged from R20.
// ============================================================================

typedef _Float16 f16;
typedef _Float16 f16x8 __attribute__((ext_vector_type(8)));
typedef _Float16 f16x4 __attribute__((ext_vector_type(4)));
typedef _Float16 f16x2 __attribute__((ext_vector_type(2)));
typedef float f32x4 __attribute__((ext_vector_type(4)));

__device__ __forceinline__ void gl_lds16(const void* g, void* l) {
  __builtin_amdgcn_global_load_lds(
      (const __attribute__((address_space(1))) void*)g,
      (__attribute__((address_space(3))) void*)l, 16, 0, 0);
}

__device__ __forceinline__ float dot8(f16x8 a, f16x8 b) {
#if __has_builtin(__builtin_amdgcn_fdot2)
  float s = 0.f;
#pragma unroll
  for (int j = 0; j < 4; ++j) {
    f16x2 av, bv;
    av[0] = a[2 * j]; av[1] = a[2 * j + 1];
    bv[0] = b[2 * j]; bv[1] = b[2 * j + 1];
    s = __builtin_amdgcn_fdot2(av, bv, s, false);
  }
  return s;
#else
  float s = 0.f;
#pragma unroll
  for (int i = 0; i < 8; ++i) s = fmaf((float)a[i], (float)b[i], s);
  return s;
#endif
}

// swizzled byte offset of the 16B half-chunk (rs, h) in the P LDS tile.
__device__ __forceinline__ int pswz(int rs, int h) {
  return (((rs * 2 + h) ^ (rs & 7)) * 16);
}

// --------- im2col: x[512,1,28,28] fp32 -> A16[m=204800][96] f16 ------------
__global__ void im2col_kernel(const float* __restrict__ x, f16* __restrict__ A)
{
  const int c = blockIdx.x * 256 + threadIdx.x;    // 2,457,600 exact
  const int m = c / 12, kc = c - m * 12;
  const int b = m / 400, rem = m - b * 400;
  const int oy = rem / 20, ox = rem - oy * 20;
  const float* xb = x + b * 784;
  f16x8 v;
#pragma unroll
  for (int j = 0; j < 8; ++j) {
    const int k = kc * 8 + j;
    float val = 0.f;
    if (k < 81) {
      const int ky = k / 9, kx = k - ky * 9;
      val = xb[(oy + ky) * 28 + ox + kx];
    }
    v[j] = (f16)val;
  }
  *(f16x8*)&A[(size_t)m * 96 + kc * 8] = v;
}

// --------- c1trans: conv1_w fp32 [256][81] -> wt1 f16 [256][96] (pad 0) ----
__global__ void c1trans_kernel(const float* __restrict__ w, f16* __restrict__ wt1)
{
  const int idx = blockIdx.x * 256 + threadIdx.x;  // 24576 exact
  const int oc = idx / 96, k = idx - oc * 96;
  wt1[idx] = (k < 81) ? (f16)w[oc * 81 + k] : (f16)0.f;
}

// --------- conv1 GEMM: ht[m][oc] = relu(A16 @ wt1^T + bias) ----------------
__global__ __launch_bounds__(256) void conv1_mfma_kernel(
    const f16* __restrict__ A, const f16* __restrict__ wt1,
    const float* __restrict__ bias, f16* __restrict__ ht)
{
  __shared__ f16 sm[8192];            // As[0..4096) | Bs[4096..8192)
  const int t = threadIdx.x;
  const int wv = t >> 6, lane = t & 63;
  const int id = blockIdx.x;
  const int mb = id >> 1, nb = id & 1;
  const int m0 = mb * 128, n0 = nb * 128;

  const int chunk = (lane & 3) ^ ((lane >> 3) & 3);
  long aoff[2], boff[2];
#pragma unroll
  for (int i = 0; i < 2; ++i) {
    const int r = wv * 32 + i * 16 + (lane >> 2);
    aoff[i] = (long)(m0 + r) * 192 + chunk * 16;
    boff[i] = (long)(n0 + r) * 192 + chunk * 16;
  }
  const char* ac = (const char*)A;
  const char* bc = (const char*)wt1;

  const int lrow = lane & 15, quad = lane >> 4;
  const int qx = quad ^ ((lrow >> 1) & 3);
  const int wm = wv & 1, wn = wv >> 1;
  f32x4 acc[4][4] = {};

  for (int s = 0; s < 3; ++s) {
    const long kstep = (long)s * 64;
    __syncthreads();
    {
      char* dA = (char*)sm + wv * 2048;
      char* dB = (char*)sm + 8192 + wv * 2048;
      gl_lds16(ac + aoff[0] + kstep, dA);
      gl_lds16(ac + aoff[1] + kstep, dA + 1024);
      gl_lds16(bc + boff[0] + kstep, dB);
      gl_lds16(bc + boff[1] + kstep, dB + 1024);
    }
    __syncthreads();
    const f16* As = sm;
    const f16* Bs = sm + 4096;
    f16x8 af[4], bf[4];
#pragma unroll
    for (int mt = 0; mt < 4; ++mt)
      af[mt] = *(const f16x8*)&As[(wm * 64 + mt * 16 + lrow) * 32 + qx * 8];
#pragma unroll
    for (int nt = 0; nt < 4; ++nt)
      bf[nt] = *(const f16x8*)&Bs[(wn * 64 + nt * 16 + lrow) * 32 + qx * 8];
#pragma unroll
    for (int mt = 0; mt < 4; ++mt)
#pragma unroll
      for (int nt = 0; nt < 4; ++nt)
        acc[mt][nt] = __builtin_amdgcn_mfma_f32_16x16x32_f16(
            af[mt], bf[nt], acc[mt][nt], 0, 0, 0);
  }

  // epilogue: ht[m*256 + oc] = relu(acc + bias[oc]) as f16 (NHWC, y/x in m)
#pragma unroll
  for (int nt = 0; nt < 4; ++nt) {
    const int n = n0 + wn * 64 + nt * 16 + lrow;          // col=lane&15
    const float bv = bias[n];
#pragma unroll
    for (int mt = 0; mt < 4; ++mt) {
      const int mbase = m0 + wm * 64 + mt * 16 + quad * 4; // row=quad*4+reg
#pragma unroll
      for (int rg = 0; rg < 4; ++rg)
        ht[(size_t)(mbase + rg) * 256 + n] =
            (f16)fmaxf(acc[mt][nt][rg] + bv, 0.f);
    }
  }
}

// --------- wtrans: prim_w fp32 [oc][ic][kykx] -> wt fp16 [oc][kykx][ic] ----
__global__ __launch_bounds__(256) void wtrans_kernel(
    const float* __restrict__ w, f16* __restrict__ wt)
{
  __shared__ float tile[64 * 83];
  const int oc = blockIdx.x;
  const int icq = blockIdx.y;
  const int t = threadIdx.x;
  const float* src = w + (size_t)oc * 20736 + (size_t)icq * 64 * 81;
  for (int idx = t; idx < 5184; idx += 256) {
    const int ici = idx / 81, kk = idx - ici * 81;
    tile[ici * 83 + kk] = src[idx];
  }
  __syncthreads();
  f16* dst = wt + (size_t)oc * 20736 + icq * 64;
  for (int idx = t; idx < 5184; idx += 256) {
    const int kk = idx >> 6, ici = idx & 63;
    dst[kk * 256 + ici] = (f16)tile[ici * 83 + kk];
  }
}

// ---------------- primary caps conv: MFMA implicit GEMM, split-K 8 ---------
// grid 2304 = 144 mb x 2 nb x 8 ks = exactly 3 rounds at 3 blocks/CU.
__global__ __launch_bounds__(256) void prim_mfma_kernel(
    const f16* __restrict__ ht, const f16* __restrict__ wt,
    f16* __restrict__ part)
{
  __shared__ f16 sm[24576];           // 48 KB: 3 buffers of [A 8KB | B 8KB]
  const int t = threadIdx.x;
  const int wv = t >> 6, lane = t & 63;
  const int id = blockIdx.x;
  const int ks = (id >> 3) & 7;                   // 8 K-slices
  const int nb = (id >> 6) & 1;
  const int mb = (id & 7) + 8 * (id >> 7);        // same-mb ids === mod 8
  const int m0 = mb * 128, n0 = nb * 128;

  const int chunk = (lane & 3) ^ ((lane >> 3) & 3);
  long aoff[2], boff[2];
#pragma unroll
  for (int i = 0; i < 2; ++i) {
    const int r = wv * 32 + i * 16 + (lane >> 2);
    const int m = m0 + r;
    const int b = m / 36, pos = m - b * 36;
    const int oy = pos / 6, ox = pos - oy * 6;
    aoff[i] = (long)(((b * 20 + 2 * oy) * 20 + 2 * ox) * 256) * 2 + chunk * 16;
    boff[i] = (long)(n0 + r) * 41472 + chunk * 16;   // oc*81*256*2
  }
  const char* htc = (const char*)ht;
  const char* wtc = (const char*)wt;

  const int lrow = lane & 15, quad = lane >> 4;
  const int qx = quad ^ ((lrow >> 1) & 3);
  const int wm = wv & 1, wn = wv >> 1;
  f32x4 acc[4][4] = {};

  const int s0 = ks * 81;             // 81 stages per slice

#define STAGE(S, BUFB)                                                        \
  {                                                                           \
    const int kykx = (S) >> 3, icb = (S) & 7;                                 \
    const int ky = kykx / 9, kx = kykx - ky * 9;                              \
    const long astep = (long)((((ky * 20 + kx) * 256) + icb * 32) * 2);       \
    const long bstep = (long)(((kykx * 256) + icb * 32) * 2);                 \
    char* dA = (char*)sm + (BUFB) + wv * 2048;                                \
    char* dB = (char*)sm + (BUFB) + 8192 + wv * 2048;                         \
    gl_lds16(htc + aoff[0] + astep, dA);                                      \
    gl_lds16(htc + aoff[1] + astep, dA + 1024);                               \
    gl_lds16(wtc + boff[0] + bstep, dB);                                      \
    gl_lds16(wtc + boff[1] + bstep, dB + 1024);                               \
  }

#define CONSUME(BUFI)                                                         \
  {                                                                           \
    const f16* As = sm + (BUFI);                                              \
    const f16* Bs = sm + (BUFI) + 4096;                                       \
    f16x8 af[4], bf[4];                                                       \
    _Pragma("unroll") for (int mt = 0; mt < 4; ++mt)                          \
        af[mt] = *(const f16x8*)&As[(wm * 64 + mt * 16 + lrow) * 32 + qx * 8];\
    _Pragma("unroll") for (int nt = 0; nt < 4; ++nt)                          \
        bf[nt] = *(const f16x8*)&Bs[(wn * 64 + nt * 16 + lrow) * 32 + qx * 8];\
    _Pragma("unroll") for (int mt = 0; mt < 4; ++mt)                          \
        _Pragma("unroll") for (int nt = 0; nt < 4; ++nt)                      \
            acc[mt][nt] = __builtin_amdgcn_mfma_f32_16x16x32_f16(             \
                af[mt], bf[nt], acc[mt][nt], 0, 0, 0);                        \
  }

  // depth-2 pipeline, 3 buffers (byte offsets 0 / 16384 / 32768)
  STAGE(s0, 0);
  STAGE(s0 + 1, 16384);
  int bS = 32768;                     // stage target:   (K+2)%3
  int bC = 0;                         // consume buffer:  K   %3
  for (int K = 0; K < 79; ++K) {
    asm volatile("s_waitcnt vmcnt(4)" ::: "memory");  // own stage-K writes done
    __builtin_amdgcn_s_barrier();                     // publish to all waves
    asm volatile("" ::: "memory");
    STAGE(s0 + K + 2, bS);
    __builtin_amdgcn_s_setprio(1);
    CONSUME(bC >> 1);
    __builtin_amdgcn_s_setprio(0);
    bS += 16384; if (bS == 49152) bS = 0;
    bC += 16384; if (bC == 49152) bC = 0;
  }
  // K = 79: stages 79,80 in flight; wait 79 (4 newest = stage 80 may fly)
  asm volatile("s_waitcnt vmcnt(4)" ::: "memory");
  __builtin_amdgcn_s_barrier();
  asm volatile("" ::: "memory");
  __builtin_amdgcn_s_setprio(1);
  CONSUME(bC >> 1);
  __builtin_amdgcn_s_setprio(0);
  bC += 16384; if (bC == 49152) bC = 0;
  // K = 80: wait everything
  asm volatile("s_waitcnt vmcnt(0)" ::: "memory");
  __builtin_amdgcn_s_barrier();
  asm volatile("" ::: "memory");
  CONSUME(bC >> 1);
#undef STAGE
#undef CONSUME

  // epilogue: f16 partials, 8 slices of [18432][256], permuted np layout
  f16* pp = part + (size_t)ks * 4718592;
#pragma unroll
  for (int mt = 0; mt < 4; ++mt) {
    const int mbase = m0 + wm * 64 + mt * 16 + quad * 4;
#pragma unroll
    for (int nt = 0; nt < 4; ++nt) {
      const int n = n0 + wn * 64 + nt * 16 + lrow;
      const int np = (n & 31) * 8 + (n >> 5);
#pragma unroll
      for (int rg = 0; rg < 4; ++rg)
        pp[(size_t)(mbase + rg) * 256 + np] = (f16)acc[mt][nt][rg];
    }
  }
}

// --------- split-K(8) reduce + bias + squash -> u16[512][rs=pos*32+cc][8] --
__global__ void squash_kernel(const f16* __restrict__ part,
                              const float* __restrict__ bias,
                              f16* __restrict__ u16)
{
  const int tid = blockIdx.x * 256 + threadIdx.x;   // (b*36+pos)*32 + cc
  if (tid >= 512 * 36 * 32) return;
  const int cc = tid & 31;
  const int row = tid >> 5;                         // b*36 + pos
  const int b = row / 36;
  const int pos = row - b * 36;
  const f16* p = part + (size_t)row * 256 + cc * 8;
  float v[8] = {};
#pragma unroll
  for (int ksl = 0; ksl < 8; ++ksl) {
    const f16x8 a = *(const f16x8*)(p + (size_t)ksl * 4718592);
#pragma unroll
    for (int i = 0; i < 8; ++i) v[i] += (float)a[i];
  }
  float sq = 0.f;
#pragma unroll
  for (int i = 0; i < 8; ++i) {
    v[i] += bias[i * 32 + cc];
    sq = fmaf(v[i], v[i], sq);
  }
  const float scale = sq / ((1.f + sq) * sqrtf(sq));
  f16x8 st;
#pragma unroll
  for (int i = 0; i < 8; ++i) st[i] = (f16)(v[i] * scale);
  *(f16x8*)&u16[(size_t)(b * 1152 + pos * 32 + cc) * 8] = st;   // contiguous
}

// --------- rwprep: route_w f32 [c][r_true][8][16] -> rwh f16 [c][o][rs][kk] -
__global__ __launch_bounds__(256) void rwprep_kernel(
    const float* __restrict__ rw, f16* __restrict__ rwh)
{
  __shared__ float tile[64][129];
  const int rs0 = blockIdx.x * 64;      // 18 chunks
  const int c   = blockIdx.y;           // [0,10)
  const int t   = threadIdx.x;
  // coalesced read: 64 rows x 128 f32
  for (int idx = t; idx < 64 * 128; idx += 256) {
    const int rsl = idx >> 7, j = idx & 127;
    const int rs = rs0 + rsl;
    const int pos = rs >> 5, cc = rs & 31;
    const int r_true = cc * 36 + pos;
    tile[rsl][j] = rw[(size_t)(c * 1152 + r_true) * 128 + j];
  }
  __syncthreads();
  // coalesced write: for each o, 64 rs x 8 kk consecutive f16
  for (int idx = t; idx < 16 * 64 * 8; idx += 256) {
    const int o = idx >> 9, rem = idx & 511;
    const int rsl = rem >> 3, kk = rem & 7;
    rwh[((size_t)(c * 16 + o) * 1152 + rs0 + rsl) * 8 + kk] =
        (f16)tile[rsl][kk * 16 + o];
  }
}

// ---------------- FUSED priors + dynamic routing, one block per (b,c) ------
// 384 threads, nk=3 uniform. P in LDS f16 (XOR-swizzled). No sched fences in
// priors: full row load-batches + cross-row pipelining.
__device__ __forceinline__ float wave_sum(float v) {
#pragma unroll
  for (int off = 32; off > 0; off >>= 1) v += __shfl_xor(v, off);
  return v;
}
__device__ __forceinline__ float wave_max(float v) {
#pragma unroll
  for (int off = 32; off > 0; off >>= 1) v = fmaxf(v, __shfl_xor(v, off));
  return v;
}

__global__ __launch_bounds__(384, 5) void routing_kernel(
    const f16* __restrict__ u16, const f16* __restrict__ rwh,
    float* __restrict__ caps)
{
  __shared__ __align__(16) f16 Pl[1152 * 16];   // 36,864 B, swizzled
  __shared__ float xred[6 * 17];
  const int c = blockIdx.x % 10;
  const int b = blockIdx.x / 10;
  const int t = threadIdx.x;            // 0..383
  const int wid = t >> 6;               // 0..5
  const int lane = t & 63;

  const f16* ub = u16 + (size_t)b * 9216;           // b*1152*8
  const f16* wb = rwh + (size_t)c * 147456;         // c*16*1152*8
  char* Pb = (char*)Pl;

  float psum[16];
#pragma unroll
  for (int o = 0; o < 16; ++o) psum[o] = 0.f;

  // ---- priors: per row, compute P_k[16] in regs, store f16 row to LDS ----
#pragma unroll
  for (int k = 0; k < 3; ++k) {
    const int rs = t + k * 384;
    const f16x8 uv = *(const f16x8*)&ub[(size_t)rs * 8];
    float Pk[16];
#pragma unroll
    for (int o = 0; o < 16; ++o) {
      const f16x8 wv = *(const f16x8*)&wb[((size_t)o * 1152 + rs) * 8];
      Pk[o] = dot8(uv, wv);
    }
    f16x8 h0, h1;
#pragma unroll
    for (int j = 0; j < 8; ++j) { h0[j] = (f16)Pk[j]; h1[j] = (f16)Pk[j + 8]; }
    *(f16x8*)(Pb + pswz(rs, 0)) = h0;
    *(f16x8*)(Pb + pswz(rs, 1)) = h1;
#pragma unroll
    for (int o = 0; o < 16; ++o) psum[o] += Pk[o];
  }

  // ---- it0: v = squash(mean of P) ----
  float v[16];
  {
    float sq = 0.f;
#pragma unroll
    for (int o = 0; o < 16; ++o) {
      float p = wave_sum(psum[o]);
      if (lane == 0) xred[wid * 17 + o] = p;
    }
    __syncthreads();   // also publishes Pl writes
#pragma unroll
    for (int o = 0; o < 16; ++o) {
      float s = 0.f;
#pragma unroll
      for (int w = 0; w < 6; ++w) s += xred[w * 17 + o];
      s *= (1.f / 1152.f);
      v[o] = s;
      sq = fmaf(s, s, sq);
    }
    const float scale = sq / ((1.f + sq) * sqrtf(sq));
#pragma unroll
    for (int o = 0; o < 16; ++o) v[o] *= scale;
    __syncthreads();
  }

  // ---- lg init: lg[k] = P[rs_k][:] . v ----
  float lg[3];
#pragma unroll
  for (int k = 0; k < 3; ++k) {
    const int rs = t + k * 384;
    const f16x8 a0 = *(const f16x8*)(Pb + pswz(rs, 0));
    const f16x8 a1 = *(const f16x8*)(Pb + pswz(rs, 1));
    float a = 0.f;
#pragma unroll
    for (int j = 0; j < 8; ++j) {
      a = fmaf((float)a0[j], v[j], a);
      a = fmaf((float)a1[j], v[j + 8], a);
    }
    lg[k] = a;
  }

  for (int it = 1; it < 3; ++it) {
    float m = fmaxf(fmaxf(lg[0], lg[1]), lg[2]);
    m = wave_max(m);
    if (lane == 0) xred[wid * 17 + 16] = m;
    __syncthreads();
    float mx = xred[16];
#pragma unroll
    for (int w = 1; w < 6; ++w) mx = fmaxf(mx, xred[w * 17 + 16]);
    __syncthreads();
    float e[3];
#pragma unroll
    for (int k = 0; k < 3; ++k) e[k] = expf(lg[k] - mx);
    float pS = e[0] + e[1] + e[2];
    pS = wave_sum(pS);
    if (lane == 0) xred[wid * 17 + 16] = pS;
    // e-weighted P sums (read rows from LDS)
    float acc[16];
#pragma unroll
    for (int o = 0; o < 16; ++o) acc[o] = 0.f;
#pragma unroll
    for (int k = 0; k < 3; ++k) {
      const int rs = t + k * 384;
      const f16x8 a0 = *(const f16x8*)(Pb + pswz(rs, 0));
      const f16x8 a1 = *(const f16x8*)(Pb + pswz(rs, 1));
#pragma unroll
      for (int j = 0; j < 8; ++j) {
        acc[j]     = fmaf(e[k], (float)a0[j], acc[j]);
        acc[j + 8] = fmaf(e[k], (float)a1[j], acc[j + 8]);
      }
    }
#pragma unroll
    for (int o = 0; o < 16; ++o) {
      float p = wave_sum(acc[o]);
      if (lane == 0) xred[wid * 17 + o] = p;
    }
    __syncthreads();
    float S = 0.f;
#pragma unroll
    for (int w = 0; w < 6; ++w) S += xred[w * 17 + 16];
    const float inv = 1.f / S;
    float sq = 0.f;
#pragma unroll
    for (int o = 0; o < 16; ++o) {
      float s = 0.f;
#pragma unroll
      for (int w = 0; w < 6; ++w) s += xred[w * 17 + o];
      s *= inv;
      v[o] = s;
      sq = fmaf(s, s, sq);
    }
    const float scale = sq / ((1.f + sq) * sqrtf(sq));
#pragma unroll
    for (int o = 0; o < 16; ++o) v[o] *= scale;
    __syncthreads();
    if (it < 2) {
#pragma unroll
      for (int k = 0; k < 3; ++k) {
        const int rs = t + k * 384;
        const f16x8 a0 = *(const f16x8*)(Pb + pswz(rs, 0));
        const f16x8 a1 = *(const f16x8*)(Pb + pswz(rs, 1));
        float a = 0.f;
#pragma unroll
        for (int j = 0; j < 8; ++j) {
          a = fmaf((float)a0[j], v[j], a);
          a = fmaf((float)a1[j], v[j + 8], a);
        }
        lg[k] += a;
      }
    }
  }
  if (t == 0) {
    float* cp = &caps[(b * 10 + c) * 16];
#pragma unroll
    for (int o = 0; o < 16; ++o) cp[o] = v[o];
  }
}

// --------- classes softmax + argmax one-hot mask ---------------------------
__global__ void classes_kernel(const float* __restrict__ caps,
                               float* __restrict__ out_classes,
                               float* __restrict__ d0)
{
  const int b = blockIdx.x * 256 + threadIdx.x;
  if (b >= 512) return;
  float nrm[10];
#pragma unroll
  for (int cc = 0; cc < 10; ++cc) {
    float sq = 0.f;
#pragma unroll
    for (int o = 0; o < 16; ++o) {
      const float vv = caps[(b * 10 + cc) * 16 + o];
      sq = fmaf(vv, vv, sq);
    }
    nrm[cc] = sqrtf(sq);
  }
  float mx = nrm[0]; int cs = 0;
#pragma unroll
  for (int cc = 1; cc < 10; ++cc)
    if (nrm[cc] > mx) { mx = nrm[cc]; cs = cc; }
  float e[10], ssum = 0.f;
#pragma unroll
  for (int cc = 0; cc < 10; ++cc) { e[cc] = expf(nrm[cc] - mx); ssum += e[cc]; }
  const float inv = 1.f / ssum;
#pragma unroll
  for (int cc = 0; cc < 10; ++cc) out_classes[b * 10 + cc] = e[cc] * inv;
#pragma unroll
  for (int cc = 0; cc < 10; ++cc)
#pragma unroll
    for (int o = 0; o < 16; ++o)
      d0[b * 160 + cc * 16 + o] = (cc == cs) ? caps[(b * 10 + cc) * 16 + o] : 0.f;
}

// --------- decoder GEMM: C[M,N] = act(A[M,K] @ W[N,K]^T + bias) ------------
__global__ __launch_bounds__(256, 2) void fc_kernel(
    const float* __restrict__ A, const float* __restrict__ W,
    const float* __restrict__ bias, float* __restrict__ C,
    int N, int K, int act)
{
  __shared__ float As[64][17];
  __shared__ float Ws[64][17];
  const int t = threadIdx.x;
  const int tm = t >> 4, tn = t & 15;
  const int m0 = blockIdx.y << 6, n0 = blockIdx.x << 6;
  const int lr = t >> 2, lq = (t & 3) << 2;
  float acc[4][4] = {};
  for (int k0 = 0; k0 < K; k0 += 16) {
    const float4 av = *(const float4*)&A[(m0 + lr) * K + k0 + lq];
    float4 wv = make_float4(0.f, 0.f, 0.f, 0.f);
    const int wn = n0 + lr;
    if (wn < N) wv = *(const float4*)&W[wn * K + k0 + lq];
    __syncthreads();
    As[lr][lq+0] = av.x; As[lr][lq+1] = av.y; As[lr][lq+2] = av.z; As[lr][lq+3] = av.w;
    Ws[lr][lq+0] = wv.x; Ws[lr][lq+1] = wv.y; Ws[lr][lq+2] = wv.z; Ws[lr][lq+3] = wv.w;
    __syncthreads();
#pragma unroll
    for (int kk = 0; kk < 16; ++kk) {
      float a[4], w[4];
#pragma unroll
      for (int i = 0; i < 4; ++i) a[i] = As[tm * 4 + i][kk];
#pragma unroll
      for (int j = 0; j < 4; ++j) w[j] = Ws[tn * 4 + j][kk];
#pragma unroll
      for (int i = 0; i < 4; ++i)
#pragma unroll
        for (int j = 0; j < 4; ++j) acc[i][j] = fmaf(a[i], w[j], acc[i][j]);
    }
  }
#pragma unroll
  for (int i = 0; i < 4; ++i) {
    const int m = m0 + tm * 4 + i;
#pragma unroll
    for (int j = 0; j < 4; ++j) {
      const int n = n0 + tn * 4 + j;
      if (n < N) {
        float vv = acc[i][j] + bias[n];
        vv = act ? (1.f / (1.f + expf(-vv))) : fmaxf(vv, 0.f);
        C[m * N + n] = vv;
      }
    }
  }
}

// ============================================================================
extern "C" void kernel_launch(void* const* d_in, const int* in_sizes, int n_in,
                              void* d_out, int out_size, void* d_ws, size_t ws_size,
                              hipStream_t stream)
{
  const float* x       = (const float*)d_in[0];
  const float* conv1_w = (const float*)d_in[1];
  const float* conv1_b = (const float*)d_in[2];
  const float* prim_w  = (const float*)d_in[3];
  const float* prim_b  = (const float*)d_in[4];
  const float* route_w = (const float*)d_in[5];
  const float* dec_w1  = (const float*)d_in[6];
  const float* dec_b1  = (const float*)d_in[7];
  const float* dec_w2  = (const float*)d_in[8];
  const float* dec_b2  = (const float*)d_in[9];
  const float* dec_w3  = (const float*)d_in[10];
  const float* dec_b3  = (const float*)d_in[11];
  float* out = (float*)d_out;

  char* ws = (char*)d_ws;
  f16*   ht   = (f16*)(ws);                        // 104,857,600 B
  f16*   wtp  = (f16*)(ws + 104857600);            //  10,616,832 B
  f16*   part = (f16*)(ws + 115474432);            //  75,497,472 B (8 f16 slices)
  f16*   A16  = (f16*)(ws + 115474432);            //  39,321,600 B (overlays
                                                   //  part; dead before prim)
  f16*   wt1  = (f16*)(ws + 190971904);            //      49,152 B
  f16*   u16  = (f16*)(ws + 191021056);            //   9,437,184 B
  f16*   rwh  = (f16*)(ws);                        //   2,949,120 B (overlays
                                                   //  ht, dead after prim)
  float* caps = (float*)(ws + 200458240);          // 327,680 B
  float* d0   = (float*)(ws + 200785920);          // 327,680 B
  float* d1   = (float*)(ws + 201113600);          // 1,048,576 B
  float* d2   = (float*)(ws + 202162176);          // 2,097,152 B

  hipLaunchKernelGGL(im2col_kernel, dim3(9600), dim3(256), 0, stream, x, A16);
  hipLaunchKernelGGL(c1trans_kernel, dim3(96), dim3(256), 0, stream,
                     conv1_w, wt1);
  hipLaunchKernelGGL(conv1_mfma_kernel, dim3(3200), dim3(256), 0, stream,
                     A16, wt1, conv1_b, ht);
  hipLaunchKernelGGL(wtrans_kernel, dim3(256, 4), dim3(256), 0, stream,
                     prim_w, wtp);
  hipLaunchKernelGGL(prim_mfma_kernel, dim3(2304), dim3(256), 0, stream,
                     ht, wtp, part);
  hipLaunchKernelGGL(rwprep_kernel, dim3(18, 10), dim3(256), 0, stream,
                     route_w, rwh);
  hipLaunchKernelGGL(squash_kernel, dim3(2304), dim3(256), 0, stream,
                     part, prim_b, u16);
  hipLaunchKernelGGL(routing_kernel, dim3(5120), dim3(384), 0, stream,
                     u16, rwh, caps);
  hipLaunchKernelGGL(classes_kernel, dim3(2), dim3(256), 0, stream,
                     caps, out, d0);
  hipLaunchKernelGGL(fc_kernel, dim3(8, 8), dim3(256), 0, stream,
                     d0, dec_w1, dec_b1, d1, 512, 160, 0);
  hipLaunchKernelGGL(fc_kernel, dim3(16, 8), dim3(256), 0, stream,
                     d1, dec_w2, dec_b2, d2, 1024, 512, 0);
  hipLaunchKernelGGL(fc_kernel, dim3(13, 8), dim3(256), 0, stream,
                     d2, dec_w3, dec_b3, out + 5120, 784, 1024, 1);
}